// Round 4
// baseline (1957.876 us; speedup 1.0000x reference)
//
#include <hip/hip_runtime.h>

#define NN 50000
#define NE 800000
#define NG 64
#define BN_EPS 1e-5f

typedef unsigned short u16;
struct alignas(8) us4 { u16 x, y, z, w; };

__device__ inline float bf2f(u16 h) { return __uint_as_float((unsigned)h << 16); }
__device__ inline u16 f2bf(float f) {
  unsigned u = __float_as_uint(f);
  return (u16)((u + 0x7fff + ((u >> 16) & 1)) >> 16);
}
__device__ inline float4 ld4(const float* p, size_t i) { return *(const float4*)(p + i); }
__device__ inline float4 ld4(const u16* p, size_t i) {
  us4 q = *(const us4*)(p + i);
  return make_float4(bf2f(q.x), bf2f(q.y), bf2f(q.z), bf2f(q.w));
}
__device__ inline float ld1(const float* p, size_t i) { return p[i]; }
__device__ inline float ld1(const u16* p, size_t i) { return bf2f(p[i]); }
__device__ inline void st4(float* p, size_t i, float4 v) { *(float4*)(p + i) = v; }
__device__ inline void st4(u16* p, size_t i, float4 v) {
  us4 q; q.x = f2bf(v.x); q.y = f2bf(v.y); q.z = f2bf(v.z); q.w = f2bf(v.w);
  *(us4*)(p + i) = q;
}
__device__ inline void st1(float* p, size_t i, float v) { p[i] = v; }
__device__ inline void st1(u16* p, size_t i, float v) { p[i] = f2bf(v); }

__device__ inline int clampi(int v, int lo, int hi) {
  return v < lo ? lo : (v > hi ? hi : v);
}

// ---------------- utility ----------------
__global__ void k_zero32(unsigned* __restrict__ p, int n) {
  int i = blockIdx.x * 256 + threadIdx.x;
  if (i < n) p[i] = 0u;
}

// ---------------- CSR build ----------------
__global__ void k_count(const int* __restrict__ dst, int* __restrict__ deg) {
  int e = blockIdx.x * 256 + threadIdx.x;
  if (e < NE) atomicAdd(&deg[clampi(dst[e], 0, NN - 1)], 1);
}

__global__ void k_scan_block(const int* __restrict__ deg, int* __restrict__ excl,
                             int* __restrict__ aux) {
  __shared__ int s[256];
  int t = threadIdx.x;
  int idx = blockIdx.x * 256 + t;
  int v = (idx < NN) ? deg[idx] : 0;
  s[t] = v;
  __syncthreads();
  for (int off = 1; off < 256; off <<= 1) {
    int x = (t >= off) ? s[t - off] : 0;
    __syncthreads();
    s[t] += x;
    __syncthreads();
  }
  if (idx < NN) excl[idx] = s[t] - v;
  if (t == 255) aux[blockIdx.x] = s[255];
}

__global__ void k_scan_aux(int* aux, int nblk) {
  __shared__ int s[256];
  int t = threadIdx.x;
  int v = (t < nblk) ? aux[t] : 0;
  s[t] = v;
  __syncthreads();
  for (int off = 1; off < 256; off <<= 1) {
    int x = (t >= off) ? s[t - off] : 0;
    __syncthreads();
    s[t] += x;
    __syncthreads();
  }
  if (t < nblk) aux[t] = s[t] - v;
}

__global__ void k_fix(int* __restrict__ rowptr, const int* __restrict__ aux,
                      int* __restrict__ cursor) {
  int idx = blockIdx.x * 256 + threadIdx.x;
  if (idx < NN) {
    int v = rowptr[idx] + aux[blockIdx.x];
    rowptr[idx] = v;
    cursor[idx] = v;
  }
  if (idx == 0) rowptr[NN] = NE;
}

__global__ void k_fill(const int* __restrict__ src, const int* __restrict__ dst,
                       const float* __restrict__ ew, int* __restrict__ cursor,
                       int* __restrict__ csr_src, float* __restrict__ csr_w) {
  int e = blockIdx.x * 256 + threadIdx.x;
  if (e < NE) {
    int d = clampi(dst[e], 0, NN - 1);
    int p = atomicAdd(&cursor[d], 1);
    p = clampi(p, 0, NE - 1);
    csr_src[p] = clampi(src[e], 0, NN - 1);
    csr_w[p] = ew[e];
  }
}

// ---------------- aggregation (gather over CSR) ----------------
// F = 512: one node per block, 128 threads, 4 elems per thread
template <typename IT, typename OT>
__global__ void k_agg512(const IT* __restrict__ xin, const int* __restrict__ rowptr,
                         const int* __restrict__ csr_src, const float* __restrict__ csr_w,
                         OT* __restrict__ out) {
  int n = blockIdx.x;
  int t = threadIdx.x;  // 0..127
  int beg = rowptr[n], end = rowptr[n + 1];
  float4 acc = {0.f, 0.f, 0.f, 0.f};
  for (int e = beg; e < end; ++e) {
    int s = csr_src[e];
    float w = csr_w[e];
    float4 v = ld4(xin, (size_t)s * 512 + t * 4);
    acc.x += v.x * w; acc.y += v.y * w; acc.z += v.z * w; acc.w += v.w * w;
  }
  st4(out, (size_t)n * 512 + t * 4, acc);
}

// F = 128: two nodes per block (64 threads), 32 threads x 4 elems per node
__global__ void k_agg128(const float* __restrict__ xin, const int* __restrict__ rowptr,
                         const int* __restrict__ csr_src, const float* __restrict__ csr_w,
                         float* __restrict__ out) {
  int sub = threadIdx.x >> 5;
  int lane = threadIdx.x & 31;
  int n = blockIdx.x * 2 + sub;
  if (n >= NN) return;
  int beg = rowptr[n], end = rowptr[n + 1];
  float4 acc = {0.f, 0.f, 0.f, 0.f};
  for (int e = beg; e < end; ++e) {
    int s = csr_src[e];
    float w = csr_w[e];
    float4 v = ld4(xin, (size_t)s * 128 + lane * 4);
    acc.x += v.x * w; acc.y += v.y * w; acc.z += v.z * w; acc.w += v.w * w;
  }
  st4(out, (size_t)n * 128 + lane * 4, acc);
}

// ------- fused dual-GEMM: out = relu(BN?(agg@Wl + bias + xin@Wr)) -------
template <int FIN, int FOUT, bool BN, typename AT, typename XT, typename OT>
__global__ __launch_bounds__(256) void k_conv_gemm(
    const AT* __restrict__ agg, const XT* __restrict__ xin,
    const float* __restrict__ Wl, const float* __restrict__ Wr,
    const float* __restrict__ bias,
    const float* __restrict__ gamma, const float* __restrict__ beta,
    const float* __restrict__ mean, const float* __restrict__ var,
    OT* __restrict__ out) {
  __shared__ float As[64][17];
  __shared__ float Bs[16][68];
  int tid = threadIdx.x;
  int tx = tid & 15, ty = tid >> 4;
  int row0 = blockIdx.x * 64;
  int col0 = blockIdx.y * 64;
  float acc[4][4] = {};

  int ar = tid >> 2;         // 0..63
  int ak = (tid & 3) * 4;    // 0,4,8,12
  int bk = tid >> 4;         // 0..15
  int bc = (tid & 15) * 4;   // 0..60

  for (int t0 = 0; t0 < 2 * FIN; t0 += 16) {
    {
      int n = row0 + ar;
      int gk = t0 + ak;
      float4 av = {0.f, 0.f, 0.f, 0.f};
      if (n < NN) {
        if (gk < FIN) av = ld4(agg, (size_t)n * FIN + gk);
        else          av = ld4(xin, (size_t)n * FIN + (gk - FIN));
      }
      As[ar][ak + 0] = av.x; As[ar][ak + 1] = av.y;
      As[ar][ak + 2] = av.z; As[ar][ak + 3] = av.w;
    }
    {
      int gk = t0 + bk;
      const float* p = (gk < FIN) ? (Wl + (size_t)gk * FOUT + col0 + bc)
                                  : (Wr + (size_t)(gk - FIN) * FOUT + col0 + bc);
      float4 bv = *(const float4*)p;
      Bs[bk][bc + 0] = bv.x; Bs[bk][bc + 1] = bv.y;
      Bs[bk][bc + 2] = bv.z; Bs[bk][bc + 3] = bv.w;
    }
    __syncthreads();
#pragma unroll
    for (int kk = 0; kk < 16; ++kk) {
      float a[4], b[4];
#pragma unroll
      for (int i = 0; i < 4; ++i) a[i] = As[ty * 4 + i][kk];
#pragma unroll
      for (int j = 0; j < 4; ++j) b[j] = Bs[kk][tx * 4 + j];
#pragma unroll
      for (int i = 0; i < 4; ++i)
#pragma unroll
        for (int j = 0; j < 4; ++j) acc[i][j] += a[i] * b[j];
    }
    __syncthreads();
  }

#pragma unroll
  for (int i = 0; i < 4; ++i) {
    int n = row0 + ty * 4 + i;
    if (n >= NN) continue;
#pragma unroll
    for (int j = 0; j < 4; ++j) {
      int c = col0 + tx * 4 + j;
      float v = acc[i][j] + bias[c];
      if (BN) v = (v - mean[c]) * rsqrtf(var[c] + BN_EPS) * gamma[c] + beta[c];
      v = fmaxf(v, 0.f);
      st1(out, (size_t)n * FOUT + c, v);
    }
  }
}

// ---------------- pooling ----------------
__global__ void k_counts(const int* __restrict__ batch, float* __restrict__ cnt) {
  int g = threadIdx.x;  // 64 threads
  int lo = 0, hi = NN;
  while (lo < hi) { int m = (lo + hi) >> 1; if (batch[m] < g) lo = m + 1; else hi = m; }
  int a = lo;
  lo = 0; hi = NN;
  int g1 = g + 1;
  while (lo < hi) { int m = (lo + hi) >> 1; if (batch[m] < g1) lo = m + 1; else hi = m; }
  cnt[g] = (float)(lo - a);
}

template <typename T>
__global__ void k_pool(const T* __restrict__ h, const int* __restrict__ batch,
                       float* __restrict__ sums) {
  int f = threadIdx.x;            // 256 features
  int n0 = blockIdx.x * 128;
  int n1 = n0 + 128; if (n1 > NN) n1 = NN;
  float acc = 0.f;
  int cur = clampi(batch[n0], 0, NG - 1);
  for (int n = n0; n < n1; ++n) {
    int g = clampi(batch[n], 0, NG - 1);
    if (g != cur) {
      atomicAdd(&sums[(size_t)cur * 256 + f], acc);
      acc = 0.f;
      cur = g;
    }
    acc += ld1(h, (size_t)n * 256 + f);
  }
  atomicAdd(&sums[(size_t)cur * 256 + f], acc);
}

__global__ void k_mlp(const float* __restrict__ sums, const float* __restrict__ cnt,
                      const float* __restrict__ W4, const float* __restrict__ b4,
                      const float* __restrict__ W5, const float* __restrict__ b5,
                      float* __restrict__ out) {
  __shared__ float g[256];
  int b = blockIdx.x, t = threadIdx.x;  // 64 threads
  float inv = 1.f / fmaxf(cnt[b], 1.f);
#pragma unroll
  for (int q = 0; q < 4; ++q) g[q * 64 + t] = sums[(size_t)b * 256 + q * 64 + t] * inv;
  __syncthreads();
  float acc = 0.f;
#pragma unroll 8
  for (int k = 0; k < 256; ++k) acc += g[k] * W4[k * 64 + t];
  float a = fmaxf(acc + b4[t], 0.f) * W5[t];
  for (int off = 32; off; off >>= 1) a += __shfl_down(a, off, 64);
  if (t == 0) out[b] = fmaxf(a + b5[0], 0.f);
}

// ---------------- launcher ----------------
extern "C" void kernel_launch(void* const* d_in, const int* in_sizes, int n_in,
                              void* d_out, int out_size, void* d_ws, size_t ws_size,
                              hipStream_t stream) {
  const float* x     = (const float*)d_in[0];
  const int*   eidx  = (const int*)d_in[1];
  const float* ew    = (const float*)d_in[2];
  const int*   batch = (const int*)d_in[3];
  const float* Wl1 = (const float*)d_in[4];
  const float* bl1 = (const float*)d_in[5];
  const float* Wr1 = (const float*)d_in[6];
  const float* Wl2 = (const float*)d_in[7];
  const float* bl2 = (const float*)d_in[8];
  const float* Wr2 = (const float*)d_in[9];
  const float* Wl3 = (const float*)d_in[10];
  const float* bl3 = (const float*)d_in[11];
  const float* Wr3 = (const float*)d_in[12];
  const float* gamma = (const float*)d_in[13];
  const float* beta  = (const float*)d_in[14];
  const float* mean  = (const float*)d_in[15];
  const float* var   = (const float*)d_in[16];
  const float* W4 = (const float*)d_in[17];
  const float* b4 = (const float*)d_in[18];
  const float* W5 = (const float*)d_in[19];
  const float* b5 = (const float*)d_in[20];

  const int* src = eidx;
  const int* dst = eidx + NE;

  // --- workspace tiers; pick largest tier whose exact total fits ws_size ---
  const size_t XF = (size_t)NN * 512 * 4;  // 102,400,000 B fp32 activation
  const size_t XH = XF / 2;                // 51,200,000 B bf16
  const size_t FIXED = (size_t)NE * 4      // csr_src
                     + (size_t)NE * 4      // csr_w
                     + ((size_t)NN + 4) * 4
                     + (size_t)NN * 4
                     + 1024
                     + (size_t)NG * 256 * 4
                     + 256 * 4;            // ~6.67 MB
  const size_t needA = 2 * XF + XF + FIXED;  // ~313.9 MB
  const size_t needB = 2 * XF + XH + FIXED;  // ~262.7 MB
  int tier = (ws_size >= needA) ? 0 : (ws_size >= needB) ? 1 : 2;
  const size_t xbytes = (tier == 2) ? XH : XF;
  const size_t abytes = (tier == 0) ? XF : XH;

  char* w = (char*)d_ws;
  void* X1 = (void*)w;  w += xbytes;
  void* X2 = (void*)w;  w += xbytes;
  void* Areg = (void*)w; w += abytes;
  int*   csr_src = (int*)w;   w += (size_t)NE * 4;
  float* csr_w   = (float*)w; w += (size_t)NE * 4;
  int*   rowptr  = (int*)w;   w += ((size_t)NN + 4) * 4;
  int*   cursor  = (int*)w;   w += (size_t)NN * 4;
  int*   aux     = (int*)w;   w += 1024;
  float* sums    = (float*)w; w += (size_t)NG * 256 * 4;
  float* cnt     = (float*)w; w += 256 * 4;

  int nblk = (NN + 255) / 256;  // 196

  // CSR build
  k_zero32<<<nblk, 256, 0, stream>>>((unsigned*)cursor, NN);
  k_count<<<(NE + 255) / 256, 256, 0, stream>>>(dst, cursor);
  k_scan_block<<<nblk, 256, 0, stream>>>(cursor, rowptr, aux);
  k_scan_aux<<<1, 256, 0, stream>>>(aux, nblk);
  k_fix<<<nblk, 256, 0, stream>>>(rowptr, aux, cursor);
  k_fill<<<(NE + 255) / 256, 256, 0, stream>>>(src, dst, ew, cursor, csr_src, csr_w);

  dim3 g512((NN + 63) / 64, 512 / 64);
  dim3 g256((NN + 63) / 64, 256 / 64);
  float* A1 = (float*)Areg;  // [N,128] fp32 fits every tier

  k_agg128<<<(NN + 1) / 2, 64, 0, stream>>>(x, rowptr, csr_src, csr_w, A1);

  if (tier == 0) {
    float* h1 = (float*)X1; float* h2 = (float*)X2; float* Af = (float*)Areg;
    k_conv_gemm<128, 512, false><<<g512, 256, 0, stream>>>(
        A1, x, Wl1, Wr1, bl1, nullptr, nullptr, nullptr, nullptr, h1);
    k_agg512<<<NN, 128, 0, stream>>>(h1, rowptr, csr_src, csr_w, Af);
    k_conv_gemm<512, 512, true><<<g512, 256, 0, stream>>>(
        Af, h1, Wl2, Wr2, bl2, gamma, beta, mean, var, h2);
    k_agg512<<<NN, 128, 0, stream>>>(h2, rowptr, csr_src, csr_w, Af);
    k_conv_gemm<512, 256, false><<<g256, 256, 0, stream>>>(
        Af, h2, Wl3, Wr3, bl3, nullptr, nullptr, nullptr, nullptr, (float*)X1);
    k_zero32<<<(NG * 256 + 255) / 256, 256, 0, stream>>>((unsigned*)sums, NG * 256);
    k_pool<<<(NN + 127) / 128, 256, 0, stream>>>((const float*)X1, batch, sums);
  } else if (tier == 1) {
    float* h1 = (float*)X1; float* h2 = (float*)X2; u16* Ah = (u16*)Areg;
    k_conv_gemm<128, 512, false><<<g512, 256, 0, stream>>>(
        A1, x, Wl1, Wr1, bl1, nullptr, nullptr, nullptr, nullptr, h1);
    k_agg512<<<NN, 128, 0, stream>>>(h1, rowptr, csr_src, csr_w, Ah);
    k_conv_gemm<512, 512, true><<<g512, 256, 0, stream>>>(
        Ah, h1, Wl2, Wr2, bl2, gamma, beta, mean, var, h2);
    k_agg512<<<NN, 128, 0, stream>>>(h2, rowptr, csr_src, csr_w, Ah);
    k_conv_gemm<512, 256, false><<<g256, 256, 0, stream>>>(
        Ah, h2, Wl3, Wr3, bl3, nullptr, nullptr, nullptr, nullptr, (float*)X1);
    k_zero32<<<(NG * 256 + 255) / 256, 256, 0, stream>>>((unsigned*)sums, NG * 256);
    k_pool<<<(NN + 127) / 128, 256, 0, stream>>>((const float*)X1, batch, sums);
  } else {
    u16* h1 = (u16*)X1; u16* h2 = (u16*)X2; u16* Ah = (u16*)Areg;
    k_conv_gemm<128, 512, false><<<g512, 256, 0, stream>>>(
        A1, x, Wl1, Wr1, bl1, nullptr, nullptr, nullptr, nullptr, h1);
    k_agg512<<<NN, 128, 0, stream>>>(h1, rowptr, csr_src, csr_w, Ah);
    k_conv_gemm<512, 512, true><<<g512, 256, 0, stream>>>(
        Ah, h1, Wl2, Wr2, bl2, gamma, beta, mean, var, h2);
    k_agg512<<<NN, 128, 0, stream>>>(h2, rowptr, csr_src, csr_w, Ah);
    k_conv_gemm<512, 256, false><<<g256, 256, 0, stream>>>(
        Ah, h2, Wl3, Wr3, bl3, nullptr, nullptr, nullptr, nullptr, h1);
    k_zero32<<<(NG * 256 + 255) / 256, 256, 0, stream>>>((unsigned*)sums, NG * 256);
    k_pool<<<(NN + 127) / 128, 256, 0, stream>>>((const u16*)h1, batch, sums);
  }

  k_counts<<<1, 64, 0, stream>>>(batch, cnt);
  k_mlp<<<NG, 64, 0, stream>>>(sums, cnt, W4, b4, W5, b5, (float*)d_out);
}

// Round 6
// 1299.429 us; speedup vs baseline: 1.5067x; 1.5067x over previous
//
#include <hip/hip_runtime.h>

#define NN 50000
#define NE 800000
#define NG 64
#define BN_EPS 1e-5f

typedef unsigned short u16;
typedef unsigned int u32;
struct alignas(8) us4 { u16 x, y, z, w; };
typedef short s16x8 __attribute__((ext_vector_type(8)));
typedef float f32x4 __attribute__((ext_vector_type(4)));

__device__ inline float bf2f(u16 h) { return __uint_as_float((u32)h << 16); }
__device__ inline u16 f2bf_rne(float f) {
  u32 u = __float_as_uint(f);
  return (u16)((u + 0x7fff + ((u >> 16) & 1)) >> 16);
}
// truncation split: v = hi + lo + O(2^-16 |v|)
__device__ inline void fsplit(float v, u16& hi, u16& lo) {
  u32 u = __float_as_uint(v);
  hi = (u16)(u >> 16);
  float r = v - __uint_as_float(u & 0xFFFF0000u);
  lo = (u16)(__float_as_uint(r) >> 16);
}
__device__ inline int clampi(int v, int lo, int hi) {
  return v < lo ? lo : (v > hi ? hi : v);
}

// ---------------- utility ----------------
__global__ void k_zero32(u32* __restrict__ p, int n) {
  int i = blockIdx.x * 256 + threadIdx.x;
  if (i < n) p[i] = 0u;
}

// ---------------- CSR build (proven round 4) ----------------
__global__ void k_count(const int* __restrict__ dst, int* __restrict__ deg) {
  int e = blockIdx.x * 256 + threadIdx.x;
  if (e < NE) atomicAdd(&deg[clampi(dst[e], 0, NN - 1)], 1);
}

__global__ void k_scan_block(const int* __restrict__ deg, int* __restrict__ excl,
                             int* __restrict__ aux) {
  __shared__ int s[256];
  int t = threadIdx.x;
  int idx = blockIdx.x * 256 + t;
  int v = (idx < NN) ? deg[idx] : 0;
  s[t] = v;
  __syncthreads();
  for (int off = 1; off < 256; off <<= 1) {
    int x = (t >= off) ? s[t - off] : 0;
    __syncthreads();
    s[t] += x;
    __syncthreads();
  }
  if (idx < NN) excl[idx] = s[t] - v;
  if (t == 255) aux[blockIdx.x] = s[255];
}

__global__ void k_scan_aux(int* aux, int nblk) {
  __shared__ int s[256];
  int t = threadIdx.x;
  int v = (t < nblk) ? aux[t] : 0;
  s[t] = v;
  __syncthreads();
  for (int off = 1; off < 256; off <<= 1) {
    int x = (t >= off) ? s[t - off] : 0;
    __syncthreads();
    s[t] += x;
    __syncthreads();
  }
  if (t < nblk) aux[t] = s[t] - v;
}

__global__ void k_fix(int* __restrict__ rowptr, const int* __restrict__ aux,
                      int* __restrict__ cursor) {
  int idx = blockIdx.x * 256 + threadIdx.x;
  if (idx < NN) {
    int v = rowptr[idx] + aux[blockIdx.x];
    rowptr[idx] = v;
    cursor[idx] = v;
  }
  if (idx == 0) rowptr[NN] = NE;
}

__global__ void k_fill(const int* __restrict__ src, const int* __restrict__ dst,
                       const float* __restrict__ ew, int* __restrict__ cursor,
                       int* __restrict__ csr_src, float* __restrict__ csr_w) {
  int e = blockIdx.x * 256 + threadIdx.x;
  if (e < NE) {
    int d = clampi(dst[e], 0, NN - 1);
    int p = atomicAdd(&cursor[d], 1);
    p = clampi(p, 0, NE - 1);
    csr_src[p] = clampi(src[e], 0, NN - 1);
    csr_w[p] = ew[e];
  }
}

// ---------------- weight transpose + split: Wt[n][k] hi/lo ----------------
__global__ void k_splitw(const float* __restrict__ Wl, const float* __restrict__ Wr,
                         int FIN, int FOUT, u16* __restrict__ th, u16* __restrict__ tl) {
  int k = blockIdx.y * 256 + threadIdx.x;
  int n = blockIdx.x;
  int K = 2 * FIN;
  if (k >= K) return;
  float v = (k < FIN) ? Wl[(size_t)k * FOUT + n] : Wr[(size_t)(k - FIN) * FOUT + n];
  u16 hi, lo;
  fsplit(v, hi, lo);
  th[(size_t)n * K + k] = hi;
  tl[(size_t)n * K + k] = lo;
}

// ---------------- aggregation: gather, output split planes ----------------
// layer 1: fp32 x [N][128] -> split agg [N][128]
template <bool ALO>
__global__ void k_agg128s(const float* __restrict__ x, const int* __restrict__ rowptr,
                          const int* __restrict__ csr_src, const float* __restrict__ csr_w,
                          u16* __restrict__ oh, u16* __restrict__ ol) {
  int sub = threadIdx.x >> 5;
  int lane = threadIdx.x & 31;
  int n = blockIdx.x * 2 + sub;
  if (n >= NN) return;
  int beg = rowptr[n], end = rowptr[n + 1];
  float4 acc = {0.f, 0.f, 0.f, 0.f};
  for (int e = beg; e < end; ++e) {
    int s = csr_src[e];
    float w = csr_w[e];
    float4 v = *(const float4*)(x + (size_t)s * 128 + lane * 4);
    acc.x += v.x * w; acc.y += v.y * w; acc.z += v.z * w; acc.w += v.w * w;
  }
  size_t o = (size_t)n * 128 + lane * 4;
  if (ALO) {
    us4 h4, l4;
    fsplit(acc.x, h4.x, l4.x); fsplit(acc.y, h4.y, l4.y);
    fsplit(acc.z, h4.z, l4.z); fsplit(acc.w, h4.w, l4.w);
    *(us4*)(oh + o) = h4;
    *(us4*)(ol + o) = l4;
  } else {
    us4 h4;
    h4.x = f2bf_rne(acc.x); h4.y = f2bf_rne(acc.y);
    h4.z = f2bf_rne(acc.z); h4.w = f2bf_rne(acc.w);
    *(us4*)(oh + o) = h4;
  }
}

// layers 2/3: split h [N][512] -> split agg [N][512]
template <bool ALO>
__global__ void k_agg512s(const u16* __restrict__ xh, const u16* __restrict__ xl,
                          const int* __restrict__ rowptr, const int* __restrict__ csr_src,
                          const float* __restrict__ csr_w,
                          u16* __restrict__ oh, u16* __restrict__ ol) {
  int n = blockIdx.x;
  int t = threadIdx.x;  // 0..127
  int beg = rowptr[n], end = rowptr[n + 1];
  float4 acc = {0.f, 0.f, 0.f, 0.f};
  for (int e = beg; e < end; ++e) {
    int s = csr_src[e];
    float w = csr_w[e];
    size_t o = (size_t)s * 512 + t * 4;
    us4 h4 = *(const us4*)(xh + o);
    us4 l4 = *(const us4*)(xl + o);
    acc.x += (bf2f(h4.x) + bf2f(l4.x)) * w;
    acc.y += (bf2f(h4.y) + bf2f(l4.y)) * w;
    acc.z += (bf2f(h4.z) + bf2f(l4.z)) * w;
    acc.w += (bf2f(h4.w) + bf2f(l4.w)) * w;
  }
  size_t o = (size_t)n * 512 + t * 4;
  if (ALO) {
    us4 h4, l4;
    fsplit(acc.x, h4.x, l4.x); fsplit(acc.y, h4.y, l4.y);
    fsplit(acc.z, h4.z, l4.z); fsplit(acc.w, h4.w, l4.w);
    *(us4*)(oh + o) = h4;
    *(us4*)(ol + o) = l4;
  } else {
    us4 h4;
    h4.x = f2bf_rne(acc.x); h4.y = f2bf_rne(acc.y);
    h4.z = f2bf_rne(acc.z); h4.w = f2bf_rne(acc.w);
    *(us4*)(oh + o) = h4;
  }
}

// ------- split-bf16 MFMA dual-GEMM: out = relu(BN?(A@Wcat + bias)) -------
// A = [agg | xin] along K (K = 2*FIN). BM=128, BN=128, BK=64, 4 waves (2x2).
template <int FIN, int FOUT, bool BNORM, bool XF32, bool ALO, bool OSPLIT>
__global__ __launch_bounds__(256) void k_gemm(
    const u16* __restrict__ Agh, const u16* __restrict__ Agl,
    const u16* __restrict__ Xh, const u16* __restrict__ Xl,
    const float* __restrict__ Xf,
    const u16* __restrict__ Wth, const u16* __restrict__ Wtl,
    const float* __restrict__ bias,
    const float* __restrict__ gamma, const float* __restrict__ beta,
    const float* __restrict__ mean, const float* __restrict__ var,
    u16* __restrict__ Oh, u16* __restrict__ Ol, float* __restrict__ Of) {
  constexpr int K = 2 * FIN;
  __shared__ u16 AhS[128 * 64];
  __shared__ u16 AlS[128 * 64];
  int tid = threadIdx.x;
  int wid = tid >> 6, l = tid & 63;
  int wr = wid >> 1, wc = wid & 1;
  int n0 = blockIdx.x * 128, c0 = blockIdx.y * 128;
  f32x4 acc[4][4] = {};

  int srow = tid >> 1;           // 0..127
  int skb = (tid & 1) * 32;      // 0 or 32
  int grow = n0 + srow;
  if (grow >= NN) grow = NN - 1;

  for (int k0 = 0; k0 < K; k0 += 64) {
    __syncthreads();
    // ---- stage A tile [128][64] as split bf16 into swizzled LDS ----
    if (XF32 && k0 >= FIN) {
      size_t base = (size_t)grow * FIN + (k0 - FIN) + skb;
#pragma unroll
      for (int q = 0; q < 4; ++q) {
        u16 hv[8], lv[8];
#pragma unroll
        for (int jj = 0; jj < 2; ++jj) {
          float4 a4 = *(const float4*)(Xf + base + q * 8 + jj * 4);
          fsplit(a4.x, hv[jj * 4 + 0], lv[jj * 4 + 0]);
          fsplit(a4.y, hv[jj * 4 + 1], lv[jj * 4 + 1]);
          fsplit(a4.z, hv[jj * 4 + 2], lv[jj * 4 + 2]);
          fsplit(a4.w, hv[jj * 4 + 3], lv[jj * 4 + 3]);
        }
        int byte = (srow * 128 + (skb + q * 8) * 2) ^ ((srow & 7) << 4);
        *(uint4*)((char*)AhS + byte) = *(uint4*)hv;
        *(uint4*)((char*)AlS + byte) = *(uint4*)lv;
      }
    } else {
      const u16* sh;
      const u16* sl;
      size_t base;
      if (k0 < FIN) { sh = Agh; sl = Agl; base = (size_t)grow * FIN + k0 + skb; }
      else          { sh = Xh;  sl = Xl;  base = (size_t)grow * FIN + (k0 - FIN) + skb; }
      bool haveLo = (k0 < FIN) ? ALO : true;
#pragma unroll
      for (int q = 0; q < 4; ++q) {
        uint4 hv = *(const uint4*)(sh + base + q * 8);
        uint4 lv = make_uint4(0u, 0u, 0u, 0u);
        if (haveLo) lv = *(const uint4*)(sl + base + q * 8);
        int byte = (srow * 128 + (skb + q * 8) * 2) ^ ((srow & 7) << 4);
        *(uint4*)((char*)AhS + byte) = hv;
        *(uint4*)((char*)AlS + byte) = lv;
      }
    }
    __syncthreads();

    // ---- compute: 2 k-sub-steps of 32 ----
#pragma unroll
    for (int ks = 0; ks < 2; ++ks) {
      int kg = k0 + ks * 32 + ((l >> 4) << 3);
      s16x8 bh[4], bl[4];
#pragma unroll
      for (int n = 0; n < 4; ++n) {
        int col = c0 + wc * 64 + n * 16 + (l & 15);
        bh[n] = *(const s16x8*)(Wth + (size_t)col * K + kg);
        bl[n] = *(const s16x8*)(Wtl + (size_t)col * K + kg);
      }
#pragma unroll
      for (int m = 0; m < 4; ++m) {
        int row = wr * 64 + m * 16 + (l & 15);
        int byte = (row * 128 + ks * 64 + ((l >> 4) << 4)) ^ ((row & 7) << 4);
        s16x8 ah = *(const s16x8*)((const char*)AhS + byte);
        s16x8 al = *(const s16x8*)((const char*)AlS + byte);
#pragma unroll
        for (int n = 0; n < 4; ++n) {
          acc[m][n] = __builtin_amdgcn_mfma_f32_16x16x32_bf16(ah, bh[n], acc[m][n], 0, 0, 0);
          acc[m][n] = __builtin_amdgcn_mfma_f32_16x16x32_bf16(ah, bl[n], acc[m][n], 0, 0, 0);
          acc[m][n] = __builtin_amdgcn_mfma_f32_16x16x32_bf16(al, bh[n], acc[m][n], 0, 0, 0);
        }
      }
    }
  }

  // ---- epilogue: bias -> BN? -> relu -> store ----
#pragma unroll
  for (int m = 0; m < 4; ++m) {
    int rowb = n0 + wr * 64 + m * 16 + ((l >> 4) << 2);
#pragma unroll
    for (int n = 0; n < 4; ++n) {
      int col = c0 + wc * 64 + n * 16 + (l & 15);
      float bs = bias[col];
      float sc = 1.f, sf = 0.f;
      if (BNORM) {
        sc = rsqrtf(var[col] + BN_EPS) * gamma[col];
        sf = beta[col] - mean[col] * sc;
      }
#pragma unroll
      for (int r = 0; r < 4; ++r) {
        int rr = rowb + r;
        if (rr < NN) {
          float v = acc[m][n][r] + bs;
          if (BNORM) v = v * sc + sf;
          v = fmaxf(v, 0.f);
          size_t o = (size_t)rr * FOUT + col;
          if (OSPLIT) {
            u16 hi, lo;
            fsplit(v, hi, lo);
            Oh[o] = hi;
            Ol[o] = lo;
          } else {
            Of[o] = v;
          }
        }
      }
    }
  }
}

// ---------------- pooling + MLP ----------------
__global__ void k_counts(const int* __restrict__ batch, float* __restrict__ cnt) {
  int g = threadIdx.x;  // 64 threads
  int lo = 0, hi = NN;
  while (lo < hi) { int m = (lo + hi) >> 1; if (batch[m] < g) lo = m + 1; else hi = m; }
  int a = lo;
  lo = 0; hi = NN;
  int g1 = g + 1;
  while (lo < hi) { int m = (lo + hi) >> 1; if (batch[m] < g1) lo = m + 1; else hi = m; }
  cnt[g] = (float)(lo - a);
}

__global__ void k_pool(const float* __restrict__ h, const int* __restrict__ batch,
                       float* __restrict__ sums) {
  int f = threadIdx.x;            // 256 features
  int n0 = blockIdx.x * 128;
  int n1 = n0 + 128; if (n1 > NN) n1 = NN;
  float acc = 0.f;
  int cur = clampi(batch[n0], 0, NG - 1);
  for (int n = n0; n < n1; ++n) {
    int g = clampi(batch[n], 0, NG - 1);
    if (g != cur) {
      atomicAdd(&sums[(size_t)cur * 256 + f], acc);
      acc = 0.f;
      cur = g;
    }
    acc += h[(size_t)n * 256 + f];
  }
  atomicAdd(&sums[(size_t)cur * 256 + f], acc);
}

__global__ void k_mlp(const float* __restrict__ sums, const float* __restrict__ cnt,
                      const float* __restrict__ W4, const float* __restrict__ b4,
                      const float* __restrict__ W5, const float* __restrict__ b5,
                      float* __restrict__ out) {
  __shared__ float g[256];
  int b = blockIdx.x, t = threadIdx.x;  // 64 threads
  float inv = 1.f / fmaxf(cnt[b], 1.f);
#pragma unroll
  for (int q = 0; q < 4; ++q) g[q * 64 + t] = sums[(size_t)b * 256 + q * 64 + t] * inv;
  __syncthreads();
  float acc = 0.f;
#pragma unroll 8
  for (int k = 0; k < 256; ++k) acc += g[k] * W4[k * 64 + t];
  float a = fmaxf(acc + b4[t], 0.f) * W5[t];
  for (int off = 32; off; off >>= 1) a += __shfl_down(a, off, 64);
  if (t == 0) out[b] = fmaxf(a + b5[0], 0.f);
}

// ---------------- launcher ----------------
extern "C" void kernel_launch(void* const* d_in, const int* in_sizes, int n_in,
                              void* d_out, int out_size, void* d_ws, size_t ws_size,
                              hipStream_t stream) {
  const float* x     = (const float*)d_in[0];
  const int*   eidx  = (const int*)d_in[1];
  const float* ew    = (const float*)d_in[2];
  const int*   batch = (const int*)d_in[3];
  const float* Wl1 = (const float*)d_in[4];
  const float* bl1 = (const float*)d_in[5];
  const float* Wr1 = (const float*)d_in[6];
  const float* Wl2 = (const float*)d_in[7];
  const float* bl2 = (const float*)d_in[8];
  const float* Wr2 = (const float*)d_in[9];
  const float* Wl3 = (const float*)d_in[10];
  const float* bl3 = (const float*)d_in[11];
  const float* Wr3 = (const float*)d_in[12];
  const float* gamma = (const float*)d_in[13];
  const float* beta  = (const float*)d_in[14];
  const float* mean  = (const float*)d_in[15];
  const float* var   = (const float*)d_in[16];
  const float* W4 = (const float*)d_in[17];
  const float* b4 = (const float*)d_in[18];
  const float* W5 = (const float*)d_in[19];
  const float* b5 = (const float*)d_in[20];

  const int* src = eidx;
  const int* dst = eidx + NE;

  // ---- workspace layout ----
  const size_t PH = (size_t)NN * 512 * 2;  // 51.2 MB plane
  const size_t WT1 = (size_t)512 * 256 * 2, WT2 = (size_t)512 * 1024 * 2,
               WT3 = (size_t)256 * 1024 * 2;
  const size_t FIXED = (size_t)NE * 4 + (size_t)NE * 4 + ((size_t)NN + 4) * 4 +
                       (size_t)NN * 4 + 1024 + (size_t)NG * 256 * 4 + 1024;
  const size_t NEED_FULL = 6 * PH + 2 * (WT1 + WT2 + WT3) + FIXED;  // ~317.7 MB
  const bool full = ws_size >= NEED_FULL;

  char* w = (char*)d_ws;
  u16* X1h = (u16*)w; w += PH;
  u16* X1l = (u16*)w; w += PH;
  u16* X2h = (u16*)w; w += PH;
  u16* X2l = (u16*)w; w += PH;
  u16* Agh = (u16*)w; w += PH;
  u16* Agl = nullptr;
  if (full) { Agl = (u16*)w; w += PH; }
  u16* Wt1h = (u16*)w; w += WT1;
  u16* Wt1l = (u16*)w; w += WT1;
  u16* Wt2h = (u16*)w; w += WT2;
  u16* Wt2l = (u16*)w; w += WT2;
  u16* Wt3h = (u16*)w; w += WT3;
  u16* Wt3l = (u16*)w; w += WT3;
  int*   csr_src = (int*)w;   w += (size_t)NE * 4;
  float* csr_w   = (float*)w; w += (size_t)NE * 4;
  int*   rowptr  = (int*)w;   w += ((size_t)NN + 4) * 4;
  int*   cursor  = (int*)w;   w += (size_t)NN * 4;
  int*   aux     = (int*)w;   w += 1024;
  float* sums    = (float*)w; w += (size_t)NG * 256 * 4;
  float* cnt     = (float*)w; w += 1024;
  float* h3 = (float*)X1h;  // layer-3 fp32 output reuses X1 region

  int nblk = (NN + 255) / 256;  // 196

  // CSR build
  k_zero32<<<nblk, 256, 0, stream>>>((u32*)cursor, NN);
  k_count<<<(NE + 255) / 256, 256, 0, stream>>>(dst, cursor);
  k_scan_block<<<nblk, 256, 0, stream>>>(cursor, rowptr, aux);
  k_scan_aux<<<1, 256, 0, stream>>>(aux, nblk);
  k_fix<<<nblk, 256, 0, stream>>>(rowptr, aux, cursor);
  k_fill<<<(NE + 255) / 256, 256, 0, stream>>>(src, dst, ew, cursor, csr_src, csr_w);

  // weight transpose+split
  k_splitw<<<dim3(512, 1), 256, 0, stream>>>(Wl1, Wr1, 128, 512, Wt1h, Wt1l);
  k_splitw<<<dim3(512, 4), 256, 0, stream>>>(Wl2, Wr2, 512, 512, Wt2h, Wt2l);
  k_splitw<<<dim3(256, 4), 256, 0, stream>>>(Wl3, Wr3, 512, 256, Wt3h, Wt3l);

  dim3 gx(391, 4), gy3(391, 2);
  if (full) {
    k_agg128s<true><<<(NN + 1) / 2, 64, 0, stream>>>(x, rowptr, csr_src, csr_w, Agh, Agl);
    k_gemm<128, 512, false, true, true, true><<<gx, 256, 0, stream>>>(
        Agh, Agl, nullptr, nullptr, x, Wt1h, Wt1l, bl1,
        nullptr, nullptr, nullptr, nullptr, X1h, X1l, nullptr);
    k_agg512s<true><<<NN, 128, 0, stream>>>(X1h, X1l, rowptr, csr_src, csr_w, Agh, Agl);
    k_gemm<512, 512, true, false, true, true><<<gx, 256, 0, stream>>>(
        Agh, Agl, X1h, X1l, nullptr, Wt2h, Wt2l, bl2,
        gamma, beta, mean, var, X2h, X2l, nullptr);
    k_agg512s<true><<<NN, 128, 0, stream>>>(X2h, X2l, rowptr, csr_src, csr_w, Agh, Agl);
    k_gemm<512, 256, false, false, true, false><<<gy3, 256, 0, stream>>>(
        Agh, Agl, X2h, X2l, nullptr, Wt3h, Wt3l, bl3,
        nullptr, nullptr, nullptr, nullptr, nullptr, nullptr, h3);
  } else {
    k_agg128s<false><<<(NN + 1) / 2, 64, 0, stream>>>(x, rowptr, csr_src, csr_w, Agh, nullptr);
    k_gemm<128, 512, false, true, false, true><<<gx, 256, 0, stream>>>(
        Agh, nullptr, nullptr, nullptr, x, Wt1h, Wt1l, bl1,
        nullptr, nullptr, nullptr, nullptr, X1h, X1l, nullptr);
    k_agg512s<false><<<NN, 128, 0, stream>>>(X1h, X1l, rowptr, csr_src, csr_w, Agh, nullptr);
    k_gemm<512, 512, true, false, false, true><<<gx, 256, 0, stream>>>(
        Agh, nullptr, X1h, X1l, nullptr, Wt2h, Wt2l, bl2,
        gamma, beta, mean, var, X2h, X2l, nullptr);
    k_agg512s<false><<<NN, 128, 0, stream>>>(X2h, X2l, rowptr, csr_src, csr_w, Agh, nullptr);
    k_gemm<512, 256, false, false, false, false><<<gy3, 256, 0, stream>>>(
        Agh, nullptr, X2h, X2l, nullptr, Wt3h, Wt3l, bl3,
        nullptr, nullptr, nullptr, nullptr, nullptr, nullptr, h3);
  }

  // pool + MLP
  k_zero32<<<(NG * 256 + 255) / 256, 256, 0, stream>>>((u32*)sums, NG * 256);
  k_pool<<<(NN + 127) / 128, 256, 0, stream>>>(h3, batch, sums);
  k_counts<<<1, 64, 0, stream>>>(batch, cnt);
  k_mlp<<<NG, 64, 0, stream>>>(sums, cnt, W4, b4, W5, b5, (float*)d_out);
}

// Round 7
// 925.973 us; speedup vs baseline: 2.1144x; 1.4033x over previous
//
#include <hip/hip_runtime.h>

#define NN 50000
#define NE 800000
#define NG 64
#define BN_EPS 1e-5f

typedef unsigned short u16;
typedef unsigned int u32;
struct alignas(8) us4 { u16 x, y, z, w; };
typedef short s16x8 __attribute__((ext_vector_type(8)));
typedef float f32x4 __attribute__((ext_vector_type(4)));

__device__ inline float bf2f(u16 h) { return __uint_as_float((u32)h << 16); }
__device__ inline u16 f2bf_rne(float f) {
  u32 u = __float_as_uint(f);
  return (u16)((u + 0x7fff + ((u >> 16) & 1)) >> 16);
}
__device__ inline int clampi(int v, int lo, int hi) {
  return v < lo ? lo : (v > hi ? hi : v);
}

// ---------------- utility ----------------
__global__ void k_zero32(u32* __restrict__ p, int n) {
  int i = blockIdx.x * 256 + threadIdx.x;
  if (i < n) p[i] = 0u;
}

// fp32 [N*128] -> bf16
__global__ void k_cvt_x(const float* __restrict__ x, u16* __restrict__ xb) {
  int i = blockIdx.x * 256 + threadIdx.x;  // one per 8 elems
  if (i >= NN * 128 / 8) return;
  size_t o = (size_t)i * 8;
  float4 a = *(const float4*)(x + o);
  float4 b = *(const float4*)(x + o + 4);
  us4 h0, h1;
  h0.x = f2bf_rne(a.x); h0.y = f2bf_rne(a.y); h0.z = f2bf_rne(a.z); h0.w = f2bf_rne(a.w);
  h1.x = f2bf_rne(b.x); h1.y = f2bf_rne(b.y); h1.z = f2bf_rne(b.z); h1.w = f2bf_rne(b.w);
  *(us4*)(xb + o) = h0;
  *(us4*)(xb + o + 4) = h1;
}

// ---------------- CSR build (proven) ----------------
__global__ void k_count(const int* __restrict__ dst, int* __restrict__ deg) {
  int e = blockIdx.x * 256 + threadIdx.x;
  if (e < NE) atomicAdd(&deg[clampi(dst[e], 0, NN - 1)], 1);
}

__global__ void k_scan_block(const int* __restrict__ deg, int* __restrict__ excl,
                             int* __restrict__ aux) {
  __shared__ int s[256];
  int t = threadIdx.x;
  int idx = blockIdx.x * 256 + t;
  int v = (idx < NN) ? deg[idx] : 0;
  s[t] = v;
  __syncthreads();
  for (int off = 1; off < 256; off <<= 1) {
    int x = (t >= off) ? s[t - off] : 0;
    __syncthreads();
    s[t] += x;
    __syncthreads();
  }
  if (idx < NN) excl[idx] = s[t] - v;
  if (t == 255) aux[blockIdx.x] = s[255];
}

__global__ void k_scan_aux(int* aux, int nblk) {
  __shared__ int s[256];
  int t = threadIdx.x;
  int v = (t < nblk) ? aux[t] : 0;
  s[t] = v;
  __syncthreads();
  for (int off = 1; off < 256; off <<= 1) {
    int x = (t >= off) ? s[t - off] : 0;
    __syncthreads();
    s[t] += x;
    __syncthreads();
  }
  if (t < nblk) aux[t] = s[t] - v;
}

__global__ void k_fix(int* __restrict__ rowptr, const int* __restrict__ aux,
                      int* __restrict__ cursor) {
  int idx = blockIdx.x * 256 + threadIdx.x;
  if (idx < NN) {
    int v = rowptr[idx] + aux[blockIdx.x];
    rowptr[idx] = v;
    cursor[idx] = v;
  }
  if (idx == 0) rowptr[NN] = NE;
}

__global__ void k_fill(const int* __restrict__ src, const int* __restrict__ dst,
                       const float* __restrict__ ew, int* __restrict__ cursor,
                       int* __restrict__ csr_src, float* __restrict__ csr_w) {
  int e = blockIdx.x * 256 + threadIdx.x;
  if (e < NE) {
    int d = clampi(dst[e], 0, NN - 1);
    int p = atomicAdd(&cursor[d], 1);
    p = clampi(p, 0, NE - 1);
    csr_src[p] = clampi(src[e], 0, NN - 1);
    csr_w[p] = ew[e];
  }
}

// ---------------- weight transpose -> bf16 Wt[n][k] ----------------
__global__ void k_wt(const float* __restrict__ Wl, const float* __restrict__ Wr,
                     int FIN, int FOUT, u16* __restrict__ t16) {
  int k = blockIdx.y * 256 + threadIdx.x;
  int n = blockIdx.x;
  int K = 2 * FIN;
  if (k >= K) return;
  float v = (k < FIN) ? Wl[(size_t)k * FOUT + n] : Wr[(size_t)(k - FIN) * FOUT + n];
  t16[(size_t)n * K + k] = f2bf_rne(v);
}

// ---------------- aggregation (bf16 gather over CSR) ----------------
// F = 512: one node per block, 128 threads, 4 elems each
__global__ void k_aggb512(const u16* __restrict__ xin, const int* __restrict__ rowptr,
                          const int* __restrict__ csr_src, const float* __restrict__ csr_w,
                          u16* __restrict__ out) {
  int n = blockIdx.x;
  int t = threadIdx.x;  // 0..127
  int beg = rowptr[n], end = rowptr[n + 1];
  float4 acc = {0.f, 0.f, 0.f, 0.f};
  for (int e = beg; e < end; ++e) {
    int s = csr_src[e];
    float w = csr_w[e];
    us4 h4 = *(const us4*)(xin + (size_t)s * 512 + t * 4);
    acc.x += bf2f(h4.x) * w; acc.y += bf2f(h4.y) * w;
    acc.z += bf2f(h4.z) * w; acc.w += bf2f(h4.w) * w;
  }
  us4 o4;
  o4.x = f2bf_rne(acc.x); o4.y = f2bf_rne(acc.y);
  o4.z = f2bf_rne(acc.z); o4.w = f2bf_rne(acc.w);
  *(us4*)(out + (size_t)n * 512 + t * 4) = o4;
}

// F = 128: two nodes per block (64 threads), 32 threads x 4 elems
__global__ void k_aggb128(const u16* __restrict__ xin, const int* __restrict__ rowptr,
                          const int* __restrict__ csr_src, const float* __restrict__ csr_w,
                          u16* __restrict__ out) {
  int sub = threadIdx.x >> 5;
  int lane = threadIdx.x & 31;
  int n = blockIdx.x * 2 + sub;
  if (n >= NN) return;
  int beg = rowptr[n], end = rowptr[n + 1];
  float4 acc = {0.f, 0.f, 0.f, 0.f};
  for (int e = beg; e < end; ++e) {
    int s = csr_src[e];
    float w = csr_w[e];
    us4 h4 = *(const us4*)(xin + (size_t)s * 128 + lane * 4);
    acc.x += bf2f(h4.x) * w; acc.y += bf2f(h4.y) * w;
    acc.z += bf2f(h4.z) * w; acc.w += bf2f(h4.w) * w;
  }
  us4 o4;
  o4.x = f2bf_rne(acc.x); o4.y = f2bf_rne(acc.y);
  o4.z = f2bf_rne(acc.z); o4.w = f2bf_rne(acc.w);
  *(us4*)(out + (size_t)n * 128 + lane * 4) = o4;
}

// ------- bf16 MFMA dual-GEMM: out = relu(BN?(A@Wcat + bias)) -------
// A = [agg | xin] (bf16 planes) along K (K = 2*FIN). BM=128, BN=128, BK=64,
// 4 waves (2x2), reg-prefetch of next A-tile under MFMA.
template <int FIN, int FOUT, bool BNORM, bool OF32>
__global__ __launch_bounds__(256) void k_gemm(
    const u16* __restrict__ A0, const u16* __restrict__ A1,
    const u16* __restrict__ Wt,
    const float* __restrict__ bias,
    const float* __restrict__ gamma, const float* __restrict__ beta,
    const float* __restrict__ mean, const float* __restrict__ var,
    u16* __restrict__ Ob, float* __restrict__ Of) {
  constexpr int K = 2 * FIN;
  __shared__ u16 AS[128 * 64];
  int tid = threadIdx.x;
  int wid = tid >> 6, l = tid & 63;
  int wr = wid >> 1, wc = wid & 1;
  int n0 = blockIdx.x * 128, c0 = blockIdx.y * 128;
  f32x4 acc[4][4] = {};

  int srow = tid >> 1;           // 0..127
  int skb = (tid & 1) * 32;      // 0 or 32
  int grow = n0 + srow;
  if (grow >= NN) grow = NN - 1;

  uint4 pf[4];
  auto loadA = [&](int k0) {
    const u16* s;
    size_t base;
    if (k0 < FIN) { s = A0; base = (size_t)grow * FIN + k0 + skb; }
    else          { s = A1; base = (size_t)grow * FIN + (k0 - FIN) + skb; }
#pragma unroll
    for (int q = 0; q < 4; ++q) pf[q] = *(const uint4*)(s + base + q * 8);
  };

  loadA(0);
  for (int k0 = 0; k0 < K; k0 += 64) {
    __syncthreads();
#pragma unroll
    for (int q = 0; q < 4; ++q) {
      int byte = (srow * 128 + (skb + q * 8) * 2) ^ ((srow & 7) << 4);
      *(uint4*)((char*)AS + byte) = pf[q];
    }
    __syncthreads();
    if (k0 + 64 < K) loadA(k0 + 64);

#pragma unroll
    for (int ks = 0; ks < 2; ++ks) {
      int kg = k0 + ks * 32 + ((l >> 4) << 3);
      s16x8 b[4];
#pragma unroll
      for (int n = 0; n < 4; ++n) {
        int col = c0 + wc * 64 + n * 16 + (l & 15);
        b[n] = *(const s16x8*)(Wt + (size_t)col * K + kg);
      }
#pragma unroll
      for (int m = 0; m < 4; ++m) {
        int row = wr * 64 + m * 16 + (l & 15);
        int byte = (row * 128 + ks * 64 + ((l >> 4) << 4)) ^ ((row & 7) << 4);
        s16x8 a = *(const s16x8*)((const char*)AS + byte);
#pragma unroll
        for (int n = 0; n < 4; ++n)
          acc[m][n] = __builtin_amdgcn_mfma_f32_16x16x32_bf16(a, b[n], acc[m][n], 0, 0, 0);
      }
    }
  }

  // ---- epilogue: bias -> BN? -> relu -> store ----
#pragma unroll
  for (int m = 0; m < 4; ++m) {
    int rowb = n0 + wr * 64 + m * 16 + ((l >> 4) << 2);
#pragma unroll
    for (int n = 0; n < 4; ++n) {
      int col = c0 + wc * 64 + n * 16 + (l & 15);
      float bs = bias[col];
      float sc = 1.f, sf = 0.f;
      if (BNORM) {
        sc = rsqrtf(var[col] + BN_EPS) * gamma[col];
        sf = beta[col] - mean[col] * sc;
      }
#pragma unroll
      for (int r = 0; r < 4; ++r) {
        int rr = rowb + r;
        if (rr < NN) {
          float v = acc[m][n][r] + bs;
          if (BNORM) v = v * sc + sf;
          v = fmaxf(v, 0.f);
          size_t o = (size_t)rr * FOUT + col;
          if (OF32) Of[o] = v;
          else      Ob[o] = f2bf_rne(v);
        }
      }
    }
  }
}

// ---------------- pooling + MLP ----------------
__global__ void k_counts(const int* __restrict__ batch, float* __restrict__ cnt) {
  int g = threadIdx.x;  // 64 threads
  int lo = 0, hi = NN;
  while (lo < hi) { int m = (lo + hi) >> 1; if (batch[m] < g) lo = m + 1; else hi = m; }
  int a = lo;
  lo = 0; hi = NN;
  int g1 = g + 1;
  while (lo < hi) { int m = (lo + hi) >> 1; if (batch[m] < g1) lo = m + 1; else hi = m; }
  cnt[g] = (float)(lo - a);
}

__global__ void k_pool(const float* __restrict__ h, const int* __restrict__ batch,
                       float* __restrict__ sums) {
  int f = threadIdx.x;            // 256 features
  int n0 = blockIdx.x * 128;
  int n1 = n0 + 128; if (n1 > NN) n1 = NN;
  float acc = 0.f;
  int cur = clampi(batch[n0], 0, NG - 1);
  for (int n = n0; n < n1; ++n) {
    int g = clampi(batch[n], 0, NG - 1);
    if (g != cur) {
      atomicAdd(&sums[(size_t)cur * 256 + f], acc);
      acc = 0.f;
      cur = g;
    }
    acc += h[(size_t)n * 256 + f];
  }
  atomicAdd(&sums[(size_t)cur * 256 + f], acc);
}

__global__ void k_mlp(const float* __restrict__ sums, const float* __restrict__ cnt,
                      const float* __restrict__ W4, const float* __restrict__ b4,
                      const float* __restrict__ W5, const float* __restrict__ b5,
                      float* __restrict__ out) {
  __shared__ float g[256];
  int b = blockIdx.x, t = threadIdx.x;  // 64 threads
  float inv = 1.f / fmaxf(cnt[b], 1.f);
#pragma unroll
  for (int q = 0; q < 4; ++q) g[q * 64 + t] = sums[(size_t)b * 256 + q * 64 + t] * inv;
  __syncthreads();
  float acc = 0.f;
#pragma unroll 8
  for (int k = 0; k < 256; ++k) acc += g[k] * W4[k * 64 + t];
  float a = fmaxf(acc + b4[t], 0.f) * W5[t];
  for (int off = 32; off; off >>= 1) a += __shfl_down(a, off, 64);
  if (t == 0) out[b] = fmaxf(a + b5[0], 0.f);
}

// ---------------- launcher ----------------
extern "C" void kernel_launch(void* const* d_in, const int* in_sizes, int n_in,
                              void* d_out, int out_size, void* d_ws, size_t ws_size,
                              hipStream_t stream) {
  const float* x     = (const float*)d_in[0];
  const int*   eidx  = (const int*)d_in[1];
  const float* ew    = (const float*)d_in[2];
  const int*   batch = (const int*)d_in[3];
  const float* Wl1 = (const float*)d_in[4];
  const float* bl1 = (const float*)d_in[5];
  const float* Wr1 = (const float*)d_in[6];
  const float* Wl2 = (const float*)d_in[7];
  const float* bl2 = (const float*)d_in[8];
  const float* Wr2 = (const float*)d_in[9];
  const float* Wl3 = (const float*)d_in[10];
  const float* bl3 = (const float*)d_in[11];
  const float* Wr3 = (const float*)d_in[12];
  const float* gamma = (const float*)d_in[13];
  const float* beta  = (const float*)d_in[14];
  const float* mean  = (const float*)d_in[15];
  const float* var   = (const float*)d_in[16];
  const float* W4 = (const float*)d_in[17];
  const float* b4 = (const float*)d_in[18];
  const float* W5 = (const float*)d_in[19];
  const float* b5 = (const float*)d_in[20];

  const int* src = eidx;
  const int* dst = eidx + NE;

  // ---- workspace layout (~176 MB total; known ws_size >= 313 MB) ----
  const size_t PH = (size_t)NN * 512 * 2;   // 51.2 MB bf16 plane
  char* w = (char*)d_ws;
  u16* X1 = (u16*)w; w += PH;               // h1; later reused as h3 fp32 [N,256]
  u16* X2 = (u16*)w; w += PH;               // h2
  u16* Ag = (u16*)w; w += PH;               // aggregation stream
  u16* Xb = (u16*)w; w += (size_t)NN * 128 * 2;  // x as bf16
  u16* Wt1 = (u16*)w; w += (size_t)512 * 256 * 2;
  u16* Wt2 = (u16*)w; w += (size_t)512 * 1024 * 2;
  u16* Wt3 = (u16*)w; w += (size_t)256 * 1024 * 2;
  int*   csr_src = (int*)w;   w += (size_t)NE * 4;
  float* csr_w   = (float*)w; w += (size_t)NE * 4;
  int*   rowptr  = (int*)w;   w += ((size_t)NN + 4) * 4;
  int*   cursor  = (int*)w;   w += (size_t)NN * 4;
  int*   aux     = (int*)w;   w += 1024;
  float* sums    = (float*)w; w += (size_t)NG * 256 * 4;
  float* cnt     = (float*)w; w += 1024;
  float* h3 = (float*)X1;   // [N,256] fp32, reuses X1 after h1 is dead

  int nblk = (NN + 255) / 256;  // 196

  // CSR build + input conversion + weight prep
  k_zero32<<<nblk, 256, 0, stream>>>((u32*)cursor, NN);
  k_count<<<(NE + 255) / 256, 256, 0, stream>>>(dst, cursor);
  k_scan_block<<<nblk, 256, 0, stream>>>(cursor, rowptr, aux);
  k_scan_aux<<<1, 256, 0, stream>>>(aux, nblk);
  k_fix<<<nblk, 256, 0, stream>>>(rowptr, aux, cursor);
  k_fill<<<(NE + 255) / 256, 256, 0, stream>>>(src, dst, ew, cursor, csr_src, csr_w);
  k_cvt_x<<<(NN * 128 / 8 + 255) / 256, 256, 0, stream>>>(x, Xb);
  k_wt<<<dim3(512, 1), 256, 0, stream>>>(Wl1, Wr1, 128, 512, Wt1);
  k_wt<<<dim3(512, 4), 256, 0, stream>>>(Wl2, Wr2, 512, 512, Wt2);
  k_wt<<<dim3(256, 4), 256, 0, stream>>>(Wl3, Wr3, 512, 256, Wt3);

  dim3 g512(391, 4), g256(391, 2);

  // Layer 1: agg(x) -> Ag[:,0:128]; h1 = relu([Ag|Xb]@Wt1 + bl1)
  k_aggb128<<<(NN + 1) / 2, 64, 0, stream>>>(Xb, rowptr, csr_src, csr_w, Ag);
  k_gemm<128, 512, false, false><<<g512, 256, 0, stream>>>(
      Ag, Xb, Wt1, bl1, nullptr, nullptr, nullptr, nullptr, X1, nullptr);

  // Layer 2: agg(h1) -> Ag; h2 = relu(BN([Ag|h1]@Wt2 + bl2))
  k_aggb512<<<NN, 128, 0, stream>>>(X1, rowptr, csr_src, csr_w, Ag);
  k_gemm<512, 512, true, false><<<g512, 256, 0, stream>>>(
      Ag, X1, Wt2, bl2, gamma, beta, mean, var, X2, nullptr);

  // Layer 3: agg(h2) -> Ag; h3 = relu([Ag|h2]@Wt3 + bl3) fp32
  k_aggb512<<<NN, 128, 0, stream>>>(X2, rowptr, csr_src, csr_w, Ag);
  k_gemm<512, 256, false, true><<<g256, 256, 0, stream>>>(
      Ag, X2, Wt3, bl3, nullptr, nullptr, nullptr, nullptr, nullptr, h3);

  // pool + MLP
  k_zero32<<<(NG * 256 + 255) / 256, 256, 0, stream>>>((u32*)sums, NG * 256);
  k_pool<<<(NN + 127) / 128, 256, 0, stream>>>(h3, batch, sums);
  k_counts<<<1, 64, 0, stream>>>(batch, cnt);
  k_mlp<<<NG, 64, 0, stream>>>(sums, cnt, W4, b4, W5, b5, (float*)d_out);
}

// Round 8
// 923.387 us; speedup vs baseline: 2.1203x; 1.0028x over previous
//
#include <hip/hip_runtime.h>

#define NN 50000
#define NE 800000
#define NG 64
#define BN_EPS 1e-5f

typedef unsigned short u16;
typedef unsigned int u32;
struct alignas(8) us4 { u16 x, y, z, w; };
typedef short s16x8 __attribute__((ext_vector_type(8)));
typedef float f32x4 __attribute__((ext_vector_type(4)));

__device__ inline float bf2f(u16 h) { return __uint_as_float((u32)h << 16); }
__device__ inline u16 f2bf_rne(float f) {
  u32 u = __float_as_uint(f);
  return (u16)((u + 0x7fff + ((u >> 16) & 1)) >> 16);
}
__device__ inline int clampi(int v, int lo, int hi) {
  return v < lo ? lo : (v > hi ? hi : v);
}

// ---------------- utility ----------------
__global__ void k_zero32(u32* __restrict__ p, int n) {
  int i = blockIdx.x * 256 + threadIdx.x;
  if (i < n) p[i] = 0u;
}

// fp32 [N*128] -> bf16
__global__ void k_cvt_x(const float* __restrict__ x, u16* __restrict__ xb) {
  int i = blockIdx.x * 256 + threadIdx.x;
  if (i >= NN * 128 / 8) return;
  size_t o = (size_t)i * 8;
  float4 a = *(const float4*)(x + o);
  float4 b = *(const float4*)(x + o + 4);
  us4 h0, h1;
  h0.x = f2bf_rne(a.x); h0.y = f2bf_rne(a.y); h0.z = f2bf_rne(a.z); h0.w = f2bf_rne(a.w);
  h1.x = f2bf_rne(b.x); h1.y = f2bf_rne(b.y); h1.z = f2bf_rne(b.z); h1.w = f2bf_rne(b.w);
  *(us4*)(xb + o) = h0;
  *(us4*)(xb + o + 4) = h1;
}

// ---------------- CSR build (proven) ----------------
__global__ void k_count(const int* __restrict__ dst, int* __restrict__ deg) {
  int e = blockIdx.x * 256 + threadIdx.x;
  if (e < NE) atomicAdd(&deg[clampi(dst[e], 0, NN - 1)], 1);
}

__global__ void k_scan_block(const int* __restrict__ deg, int* __restrict__ excl,
                             int* __restrict__ aux) {
  __shared__ int s[256];
  int t = threadIdx.x;
  int idx = blockIdx.x * 256 + t;
  int v = (idx < NN) ? deg[idx] : 0;
  s[t] = v;
  __syncthreads();
  for (int off = 1; off < 256; off <<= 1) {
    int x = (t >= off) ? s[t - off] : 0;
    __syncthreads();
    s[t] += x;
    __syncthreads();
  }
  if (idx < NN) excl[idx] = s[t] - v;
  if (t == 255) aux[blockIdx.x] = s[255];
}

__global__ void k_scan_aux(int* aux, int nblk) {
  __shared__ int s[256];
  int t = threadIdx.x;
  int v = (t < nblk) ? aux[t] : 0;
  s[t] = v;
  __syncthreads();
  for (int off = 1; off < 256; off <<= 1) {
    int x = (t >= off) ? s[t - off] : 0;
    __syncthreads();
    s[t] += x;
    __syncthreads();
  }
  if (t < nblk) aux[t] = s[t] - v;
}

__global__ void k_fix(int* __restrict__ rowptr, const int* __restrict__ aux,
                      int* __restrict__ cursor) {
  int idx = blockIdx.x * 256 + threadIdx.x;
  if (idx < NN) {
    int v = rowptr[idx] + aux[blockIdx.x];
    rowptr[idx] = v;
    cursor[idx] = v;
  }
  if (idx == 0) rowptr[NN] = NE;
}

__global__ void k_fill(const int* __restrict__ src, const int* __restrict__ dst,
                       const float* __restrict__ ew, int* __restrict__ cursor,
                       int* __restrict__ csr_src, float* __restrict__ csr_w) {
  int e = blockIdx.x * 256 + threadIdx.x;
  if (e < NE) {
    int d = clampi(dst[e], 0, NN - 1);
    int p = atomicAdd(&cursor[d], 1);
    p = clampi(p, 0, NE - 1);
    csr_src[p] = clampi(src[e], 0, NN - 1);
    csr_w[p] = ew[e];
  }
}

// --------- weight prep: Wt[n][k] = [Wl;Wr] concat along k (bf16) ---------
__global__ void k_wt(const float* __restrict__ Wl, const float* __restrict__ Wr,
                     int FIN, int FOUT, u16* __restrict__ t16) {
  int k = blockIdx.y * 256 + threadIdx.x;
  int n = blockIdx.x;
  int K = 2 * FIN;
  if (k >= K) return;
  float v = (k < FIN) ? Wl[(size_t)k * FOUT + n] : Wr[(size_t)(k - FIN) * FOUT + n];
  t16[(size_t)n * K + k] = f2bf_rne(v);
}

// --------- weight prep: Wt[n][k] = [Wl|Wr] concat along n (bf16) ---------
__global__ void k_wtn(const float* __restrict__ Wl, const float* __restrict__ Wr,
                      int Kdim, int half, u16* __restrict__ t16) {
  int k = blockIdx.y * 256 + threadIdx.x;
  int n = blockIdx.x;
  if (k >= Kdim) return;
  float v = (n < half) ? Wl[(size_t)k * half + n] : Wr[(size_t)k * half + (n - half)];
  t16[(size_t)n * Kdim + k] = f2bf_rne(v);
}

// ---------------- aggregation (bf16 gather over CSR) ----------------
__global__ void k_aggb512(const u16* __restrict__ xin, const int* __restrict__ rowptr,
                          const int* __restrict__ csr_src, const float* __restrict__ csr_w,
                          u16* __restrict__ out) {
  int n = blockIdx.x;
  int t = threadIdx.x;  // 0..127
  int beg = rowptr[n], end = rowptr[n + 1];
  float4 acc = {0.f, 0.f, 0.f, 0.f};
  for (int e = beg; e < end; ++e) {
    int s = csr_src[e];
    float w = csr_w[e];
    us4 h4 = *(const us4*)(xin + (size_t)s * 512 + t * 4);
    acc.x += bf2f(h4.x) * w; acc.y += bf2f(h4.y) * w;
    acc.z += bf2f(h4.z) * w; acc.w += bf2f(h4.w) * w;
  }
  us4 o4;
  o4.x = f2bf_rne(acc.x); o4.y = f2bf_rne(acc.y);
  o4.z = f2bf_rne(acc.z); o4.w = f2bf_rne(acc.w);
  *(us4*)(out + (size_t)n * 512 + t * 4) = o4;
}

__global__ void k_aggb128(const u16* __restrict__ xin, const int* __restrict__ rowptr,
                          const int* __restrict__ csr_src, const float* __restrict__ csr_w,
                          u16* __restrict__ out) {
  int sub = threadIdx.x >> 5;
  int lane = threadIdx.x & 31;
  int n = blockIdx.x * 2 + sub;
  if (n >= NN) return;
  int beg = rowptr[n], end = rowptr[n + 1];
  float4 acc = {0.f, 0.f, 0.f, 0.f};
  for (int e = beg; e < end; ++e) {
    int s = csr_src[e];
    float w = csr_w[e];
    us4 h4 = *(const us4*)(xin + (size_t)s * 128 + lane * 4);
    acc.x += bf2f(h4.x) * w; acc.y += bf2f(h4.y) * w;
    acc.z += bf2f(h4.z) * w; acc.w += bf2f(h4.w) * w;
  }
  us4 o4;
  o4.x = f2bf_rne(acc.x); o4.y = f2bf_rne(acc.y);
  o4.z = f2bf_rne(acc.z); o4.w = f2bf_rne(acc.w);
  *(us4*)(out + (size_t)n * 128 + lane * 4) = o4;
}

// ------- bf16 MFMA GEMM: Ob[128x128 tiles] over A=[A0|A1], Wt[n][k] -------
// FOUT fixed 512. EPI: 0 = relu(v+bias); 1 = relu(BN(v+bias)); 2 = raw v.
// A+B LDS-staged (XOR swizzle), reg-prefetch dbuf, LDS-restaged coalesced out.
template <int K, int W0, int EPI>
__global__ __launch_bounds__(256) void k_gemm(
    const u16* __restrict__ A0, const u16* __restrict__ A1,
    const u16* __restrict__ Wt, const float* __restrict__ bias,
    const float* __restrict__ gamma, const float* __restrict__ beta,
    const float* __restrict__ mean, const float* __restrict__ var,
    u16* __restrict__ Ob) {
  constexpr int FOUT = 512;
  __shared__ char LDSC[32768];
  u16* AS = (u16*)LDSC;            // 16 KB A tile [128 rows][64 k]
  u16* BS = (u16*)(LDSC + 16384);  // 16 KB B tile [128 cols][64 k]
  int tid = threadIdx.x;
  int wid = tid >> 6, l = tid & 63;
  int wr = wid >> 1, wc = wid & 1;

  // bijective XCD swizzle + quad mapping: 4 col-blocks of a row-panel adjacent
  int nwg = gridDim.x;  // 1564
  int q8 = nwg >> 3, r8 = nwg & 7;
  int xcd = blockIdx.x & 7, idx = blockIdx.x >> 3;
  int L = (xcd < r8 ? xcd * (q8 + 1) : r8 * (q8 + 1) + (xcd - r8) * q8) + idx;
  int n0 = (L >> 2) * 128, c0 = (L & 3) * 128;

  f32x4 acc[4][4] = {};
  int srow = tid >> 1;        // 0..127
  int skb = (tid & 1) * 32;   // 0 or 32
  int grow = n0 + srow;
  if (grow >= NN) grow = NN - 1;

  uint4 pfA[4], pfB[4];
  auto loadT = [&](int k0) {
    const u16* s;
    size_t base;
    if (k0 < W0) { s = A0; base = (size_t)grow * W0 + k0 + skb; }
    else         { s = A1; base = (size_t)grow * (K - W0) + (k0 - W0) + skb; }
#pragma unroll
    for (int qq = 0; qq < 4; ++qq) pfA[qq] = *(const uint4*)(s + base + qq * 8);
    size_t bb = (size_t)(c0 + srow) * K + k0 + skb;
#pragma unroll
    for (int qq = 0; qq < 4; ++qq) pfB[qq] = *(const uint4*)(Wt + bb + qq * 8);
  };

  loadT(0);
  for (int k0 = 0; k0 < K; k0 += 64) {
    __syncthreads();
#pragma unroll
    for (int qq = 0; qq < 4; ++qq) {
      int byte = (srow * 128 + (skb + qq * 8) * 2) ^ ((srow & 7) << 4);
      *(uint4*)((char*)AS + byte) = pfA[qq];
      *(uint4*)((char*)BS + byte) = pfB[qq];
    }
    __syncthreads();
    if (k0 + 64 < K) loadT(k0 + 64);

#pragma unroll
    for (int ks = 0; ks < 2; ++ks) {
      s16x8 b[4];
#pragma unroll
      for (int n = 0; n < 4; ++n) {
        int col = wc * 64 + n * 16 + (l & 15);
        int byte = (col * 128 + ks * 64 + ((l >> 4) << 4)) ^ ((col & 7) << 4);
        b[n] = *(const s16x8*)((const char*)BS + byte);
      }
#pragma unroll
      for (int m = 0; m < 4; ++m) {
        int row = wr * 64 + m * 16 + (l & 15);
        int byte = (row * 128 + ks * 64 + ((l >> 4) << 4)) ^ ((row & 7) << 4);
        s16x8 a = *(const s16x8*)((const char*)AS + byte);
#pragma unroll
        for (int n = 0; n < 4; ++n)
          acc[m][n] = __builtin_amdgcn_mfma_f32_16x16x32_bf16(a, b[n], acc[m][n], 0, 0, 0);
      }
    }
  }

  // ---- epilogue: EPI -> LDS restage (swizzled) -> coalesced 16B stores ----
  __syncthreads();
  u16* OS = (u16*)LDSC;  // [128][128] bf16 = 32 KB
#pragma unroll
  for (int n = 0; n < 4; ++n) {
    int colL = wc * 64 + n * 16 + (l & 15);
    int col = c0 + colL;
    float bs = (EPI == 2) ? 0.f : bias[col];
    float sc = 1.f, sf = 0.f;
    if (EPI == 1) {
      sc = rsqrtf(var[col] + BN_EPS) * gamma[col];
      sf = beta[col] - mean[col] * sc;
    }
#pragma unroll
    for (int m = 0; m < 4; ++m) {
      int rowL0 = wr * 64 + m * 16 + ((l >> 4) << 2);
#pragma unroll
      for (int r = 0; r < 4; ++r) {
        float v = acc[m][n][r];
        if (EPI != 2) {
          v += bs;
          if (EPI == 1) v = v * sc + sf;
          v = fmaxf(v, 0.f);
        }
        int rowL = rowL0 + r;
        int byte = (rowL * 256 + colL * 2) ^ ((rowL & 7) << 4);
        *(u16*)((char*)OS + byte) = f2bf_rne(v);
      }
    }
  }
  __syncthreads();
#pragma unroll
  for (int i = 0; i < 8; ++i) {
    int chunk = i * 256 + tid;      // 0..2047
    int rowL = chunk >> 4;          // 16 x 16B chunks per 256B row
    int cs = (chunk & 15) * 8;      // col start (u16 units)
    int rr = n0 + rowL;
    if (rr < NN) {
      int byte = (rowL * 256 + cs * 2) ^ ((rowL & 7) << 4);
      *(uint4*)(Ob + (size_t)rr * FOUT + c0 + cs) = *(const uint4*)((const char*)OS + byte);
    }
  }
}

// ------- L3 combine: h3 = relu(agg256(P) + Q + bl3), P|Q packed [N,512] -------
__global__ void k_aggcomb(const u16* __restrict__ PQ, const int* __restrict__ rowptr,
                          const int* __restrict__ csr_src, const float* __restrict__ csr_w,
                          const float* __restrict__ bl3, float* __restrict__ h3) {
  int sub = threadIdx.x >> 6;
  int lane = threadIdx.x & 63;
  int n = blockIdx.x * 2 + sub;
  if (n >= NN) return;
  int beg = rowptr[n], end = rowptr[n + 1];
  float4 acc = {0.f, 0.f, 0.f, 0.f};
  for (int e = beg; e < end; ++e) {
    int s = csr_src[e];
    float w = csr_w[e];
    us4 h4 = *(const us4*)(PQ + (size_t)s * 512 + lane * 4);  // P region: cols 0..255
    acc.x += bf2f(h4.x) * w; acc.y += bf2f(h4.y) * w;
    acc.z += bf2f(h4.z) * w; acc.w += bf2f(h4.w) * w;
  }
  us4 qv = *(const us4*)(PQ + (size_t)n * 512 + 256 + lane * 4);
  float4 bb = *(const float4*)(bl3 + lane * 4);
  float4 o;
  o.x = fmaxf(acc.x + bf2f(qv.x) + bb.x, 0.f);
  o.y = fmaxf(acc.y + bf2f(qv.y) + bb.y, 0.f);
  o.z = fmaxf(acc.z + bf2f(qv.z) + bb.z, 0.f);
  o.w = fmaxf(acc.w + bf2f(qv.w) + bb.w, 0.f);
  *(float4*)(h3 + (size_t)n * 256 + lane * 4) = o;
}

// ---------------- pooling + MLP ----------------
__global__ void k_counts(const int* __restrict__ batch, float* __restrict__ cnt) {
  int g = threadIdx.x;  // 64 threads
  int lo = 0, hi = NN;
  while (lo < hi) { int m = (lo + hi) >> 1; if (batch[m] < g) lo = m + 1; else hi = m; }
  int a = lo;
  lo = 0; hi = NN;
  int g1 = g + 1;
  while (lo < hi) { int m = (lo + hi) >> 1; if (batch[m] < g1) lo = m + 1; else hi = m; }
  cnt[g] = (float)(lo - a);
}

__global__ void k_pool(const float* __restrict__ h, const int* __restrict__ batch,
                       float* __restrict__ sums) {
  int f = threadIdx.x;  // 256 features
  int n0 = blockIdx.x * 128;
  int n1 = n0 + 128; if (n1 > NN) n1 = NN;
  float acc = 0.f;
  int cur = clampi(batch[n0], 0, NG - 1);
  for (int n = n0; n < n1; ++n) {
    int g = clampi(batch[n], 0, NG - 1);
    if (g != cur) {
      atomicAdd(&sums[(size_t)cur * 256 + f], acc);
      acc = 0.f;
      cur = g;
    }
    acc += h[(size_t)n * 256 + f];
  }
  atomicAdd(&sums[(size_t)cur * 256 + f], acc);
}

__global__ void k_mlp(const float* __restrict__ sums, const float* __restrict__ cnt,
                      const float* __restrict__ W4, const float* __restrict__ b4,
                      const float* __restrict__ W5, const float* __restrict__ b5,
                      float* __restrict__ out) {
  __shared__ float g[256];
  int b = blockIdx.x, t = threadIdx.x;  // 64 threads
  float inv = 1.f / fmaxf(cnt[b], 1.f);
#pragma unroll
  for (int q = 0; q < 4; ++q) g[q * 64 + t] = sums[(size_t)b * 256 + q * 64 + t] * inv;
  __syncthreads();
  float acc = 0.f;
#pragma unroll 8
  for (int k = 0; k < 256; ++k) acc += g[k] * W4[k * 64 + t];
  float a = fmaxf(acc + b4[t], 0.f) * W5[t];
  for (int off = 32; off; off >>= 1) a += __shfl_down(a, off, 64);
  if (t == 0) out[b] = fmaxf(a + b5[0], 0.f);
}

// ---------------- launcher ----------------
extern "C" void kernel_launch(void* const* d_in, const int* in_sizes, int n_in,
                              void* d_out, int out_size, void* d_ws, size_t ws_size,
                              hipStream_t stream) {
  const float* x     = (const float*)d_in[0];
  const int*   eidx  = (const int*)d_in[1];
  const float* ew    = (const float*)d_in[2];
  const int*   batch = (const int*)d_in[3];
  const float* Wl1 = (const float*)d_in[4];
  const float* bl1 = (const float*)d_in[5];
  const float* Wr1 = (const float*)d_in[6];
  const float* Wl2 = (const float*)d_in[7];
  const float* bl2 = (const float*)d_in[8];
  const float* Wr2 = (const float*)d_in[9];
  const float* Wl3 = (const float*)d_in[10];
  const float* bl3 = (const float*)d_in[11];
  const float* Wr3 = (const float*)d_in[12];
  const float* gamma = (const float*)d_in[13];
  const float* beta  = (const float*)d_in[14];
  const float* mean  = (const float*)d_in[15];
  const float* var   = (const float*)d_in[16];
  const float* W4 = (const float*)d_in[17];
  const float* b4 = (const float*)d_in[18];
  const float* W5 = (const float*)d_in[19];
  const float* b5 = (const float*)d_in[20];

  const int* src = eidx;
  const int* dst = eidx + NE;

  // ---- workspace layout (~176 MB; ws_size known >= 313 MB) ----
  const size_t PH = (size_t)NN * 512 * 2;  // 51.2 MB bf16 plane
  char* w = (char*)d_ws;
  u16* X1 = (u16*)w; w += PH;              // h1 bf16; later h3 fp32 [N,256]
  u16* X2 = (u16*)w; w += PH;              // h2 bf16
  u16* Ag = (u16*)w; w += PH;              // agg stream / PQ plane
  u16* Xb = (u16*)w; w += (size_t)NN * 128 * 2;
  u16* Wt1 = (u16*)w; w += (size_t)512 * 256 * 2;
  u16* Wt2 = (u16*)w; w += (size_t)512 * 1024 * 2;
  u16* Wt3 = (u16*)w; w += (size_t)512 * 512 * 2;
  int*   csr_src = (int*)w;   w += (size_t)NE * 4;
  float* csr_w   = (float*)w; w += (size_t)NE * 4;
  int*   rowptr  = (int*)w;   w += ((size_t)NN + 4) * 4;
  int*   cursor  = (int*)w;   w += (size_t)NN * 4;
  int*   aux     = (int*)w;   w += 1024;
  float* sums    = (float*)w; w += (size_t)NG * 256 * 4;
  float* cnt     = (float*)w; w += 1024;
  float* h3 = (float*)X1;  // [N,256] fp32 reuses X1 after h1 dead

  int nblk = (NN + 255) / 256;  // 196

  // CSR build + input conversion + weight prep
  k_zero32<<<nblk, 256, 0, stream>>>((u32*)cursor, NN);
  k_count<<<(NE + 255) / 256, 256, 0, stream>>>(dst, cursor);
  k_scan_block<<<nblk, 256, 0, stream>>>(cursor, rowptr, aux);
  k_scan_aux<<<1, 256, 0, stream>>>(aux, nblk);
  k_fix<<<nblk, 256, 0, stream>>>(rowptr, aux, cursor);
  k_fill<<<(NE + 255) / 256, 256, 0, stream>>>(src, dst, ew, cursor, csr_src, csr_w);
  k_cvt_x<<<(NN * 128 / 8 + 255) / 256, 256, 0, stream>>>(x, Xb);
  k_wt<<<dim3(512, 1), 256, 0, stream>>>(Wl1, Wr1, 128, 512, Wt1);
  k_wt<<<dim3(512, 4), 256, 0, stream>>>(Wl2, Wr2, 512, 512, Wt2);
  k_wtn<<<dim3(512, 2), 256, 0, stream>>>(Wl3, Wr3, 512, 256, Wt3);

  const int NWG = 391 * 4;  // 1564 (128x128 tiles over [50048 x 512])

  // Layer 1: agg(x) -> Ag; h1 = relu([Ag|Xb]@Wt1 + bl1)
  k_aggb128<<<(NN + 1) / 2, 64, 0, stream>>>(Xb, rowptr, csr_src, csr_w, Ag);
  k_gemm<256, 128, 0><<<NWG, 256, 0, stream>>>(
      Ag, Xb, Wt1, bl1, nullptr, nullptr, nullptr, nullptr, X1);

  // Layer 2: agg(h1) -> Ag; h2 = relu(BN([Ag|h1]@Wt2 + bl2))
  k_aggb512<<<NN, 128, 0, stream>>>(X1, rowptr, csr_src, csr_w, Ag);
  k_gemm<1024, 512, 1><<<NWG, 256, 0, stream>>>(
      Ag, X1, Wt2, bl2, gamma, beta, mean, var, X2);

  // Layer 3: PQ = h2 @ [Wl3|Wr3] (raw); h3 = relu(agg256(P) + Q + bl3)
  k_gemm<512, 512, 2><<<NWG, 256, 0, stream>>>(
      X2, X2, Wt3, nullptr, nullptr, nullptr, nullptr, nullptr, Ag);
  k_aggcomb<<<(NN + 1) / 2, 128, 0, stream>>>(Ag, rowptr, csr_src, csr_w, bl3, h3);

  // pool + MLP
  k_zero32<<<(NG * 256 + 255) / 256, 256, 0, stream>>>((u32*)sums, NG * 256);
  k_pool<<<(NN + 127) / 128, 256, 0, stream>>>(h3, batch, sums);
  k_counts<<<1, 64, 0, stream>>>(batch, cnt);
  k_mlp<<<NG, 64, 0, stream>>>(sums, cnt, W4, b4, W5, b5, (float*)d_out);
}

// Round 10
// 590.360 us; speedup vs baseline: 3.3164x; 1.5641x over previous
//
#include <hip/hip_runtime.h>

#define NN 50000
#define NE 800000
#define NG 64
#define BN_EPS 1e-5f

typedef unsigned short u16;
typedef unsigned int u32;
struct alignas(8) us4 { u16 x, y, z, w; };
typedef short s16x8 __attribute__((ext_vector_type(8)));
typedef float f32x4 __attribute__((ext_vector_type(4)));

__device__ inline float bf2f(u16 h) { return __uint_as_float((u32)h << 16); }
__device__ inline u16 f2bf_rne(float f) {
  u32 u = __float_as_uint(f);
  return (u16)((u + 0x7fff + ((u >> 16) & 1)) >> 16);
}
__device__ inline int clampi(int v, int lo, int hi) {
  return v < lo ? lo : (v > hi ? hi : v);
}
// async global->LDS DMA, 16B per lane; LDS dest is wave-uniform base
__device__ inline void gload_lds16(const void* g, void* l) {
  __builtin_amdgcn_global_load_lds(
      (const __attribute__((address_space(1))) u32*)g,
      (__attribute__((address_space(3))) u32*)l, 16, 0, 0);
}

// ---------------- utility ----------------
__global__ void k_zero32(u32* __restrict__ p, int n) {
  int i = blockIdx.x * 256 + threadIdx.x;
  if (i < n) p[i] = 0u;
}

// fp32 [N*128] -> bf16
__global__ void k_cvt_x(const float* __restrict__ x, u16* __restrict__ xb) {
  int i = blockIdx.x * 256 + threadIdx.x;
  if (i >= NN * 128 / 8) return;
  size_t o = (size_t)i * 8;
  float4 a = *(const float4*)(x + o);
  float4 b = *(const float4*)(x + o + 4);
  us4 h0, h1;
  h0.x = f2bf_rne(a.x); h0.y = f2bf_rne(a.y); h0.z = f2bf_rne(a.z); h0.w = f2bf_rne(a.w);
  h1.x = f2bf_rne(b.x); h1.y = f2bf_rne(b.y); h1.z = f2bf_rne(b.z); h1.w = f2bf_rne(b.w);
  *(us4*)(xb + o) = h0;
  *(us4*)(xb + o + 4) = h1;
}

// ---------------- CSR build (proven) ----------------
__global__ void k_count(const int* __restrict__ dst, int* __restrict__ deg) {
  int e = blockIdx.x * 256 + threadIdx.x;
  if (e < NE) atomicAdd(&deg[clampi(dst[e], 0, NN - 1)], 1);
}

__global__ void k_scan_block(const int* __restrict__ deg, int* __restrict__ excl,
                             int* __restrict__ aux) {
  __shared__ int s[256];
  int t = threadIdx.x;
  int idx = blockIdx.x * 256 + t;
  int v = (idx < NN) ? deg[idx] : 0;
  s[t] = v;
  __syncthreads();
  for (int off = 1; off < 256; off <<= 1) {
    int x = (t >= off) ? s[t - off] : 0;
    __syncthreads();
    s[t] += x;
    __syncthreads();
  }
  if (idx < NN) excl[idx] = s[t] - v;
  if (t == 255) aux[blockIdx.x] = s[255];
}

__global__ void k_scan_aux(int* aux, int nblk) {
  __shared__ int s[256];
  int t = threadIdx.x;
  int v = (t < nblk) ? aux[t] : 0;
  s[t] = v;
  __syncthreads();
  for (int off = 1; off < 256; off <<= 1) {
    int x = (t >= off) ? s[t - off] : 0;
    __syncthreads();
    s[t] += x;
    __syncthreads();
  }
  if (t < nblk) aux[t] = s[t] - v;
}

__global__ void k_fix(int* __restrict__ rowptr, const int* __restrict__ aux,
                      int* __restrict__ cursor) {
  int idx = blockIdx.x * 256 + threadIdx.x;
  if (idx < NN) {
    int v = rowptr[idx] + aux[blockIdx.x];
    rowptr[idx] = v;
    cursor[idx] = v;
  }
  if (idx == 0) rowptr[NN] = NE;
}

__global__ void k_fill(const int* __restrict__ src, const int* __restrict__ dst,
                       const float* __restrict__ ew, int* __restrict__ cursor,
                       int* __restrict__ csr_src, float* __restrict__ csr_w) {
  int e = blockIdx.x * 256 + threadIdx.x;
  if (e < NE) {
    int d = clampi(dst[e], 0, NN - 1);
    int p = atomicAdd(&cursor[d], 1);
    p = clampi(p, 0, NE - 1);
    csr_src[p] = clampi(src[e], 0, NN - 1);
    csr_w[p] = ew[e];
  }
}

// --------- weight prep: Wt[n][k] = [Wl;Wr] concat along k (bf16) ---------
__global__ void k_wt(const float* __restrict__ Wl, const float* __restrict__ Wr,
                     int FIN, int FOUT, u16* __restrict__ t16) {
  int k = blockIdx.y * 256 + threadIdx.x;
  int n = blockIdx.x;
  int K = 2 * FIN;
  if (k >= K) return;
  float v = (k < FIN) ? Wl[(size_t)k * FOUT + n] : Wr[(size_t)(k - FIN) * FOUT + n];
  t16[(size_t)n * K + k] = f2bf_rne(v);
}

// --------- weight prep: Wt[n][k] = [Wl|Wr] concat along n (bf16) ---------
__global__ void k_wtn(const float* __restrict__ Wl, const float* __restrict__ Wr,
                      int Kdim, int half, u16* __restrict__ t16) {
  int k = blockIdx.y * 256 + threadIdx.x;
  int n = blockIdx.x;
  if (k >= Kdim) return;
  float v = (n < half) ? Wl[(size_t)k * half + n] : Wr[(size_t)k * half + (n - half)];
  t16[(size_t)n * Kdim + k] = f2bf_rne(v);
}

// ---------------- aggregation (bf16 gather over CSR) ----------------
__global__ void k_aggb512(const u16* __restrict__ xin, const int* __restrict__ rowptr,
                          const int* __restrict__ csr_src, const float* __restrict__ csr_w,
                          u16* __restrict__ out) {
  int n = blockIdx.x;
  int t = threadIdx.x;  // 0..127
  int beg = rowptr[n], end = rowptr[n + 1];
  float4 acc = {0.f, 0.f, 0.f, 0.f};
  for (int e = beg; e < end; ++e) {
    int s = csr_src[e];
    float w = csr_w[e];
    us4 h4 = *(const us4*)(xin + (size_t)s * 512 + t * 4);
    acc.x += bf2f(h4.x) * w; acc.y += bf2f(h4.y) * w;
    acc.z += bf2f(h4.z) * w; acc.w += bf2f(h4.w) * w;
  }
  us4 o4;
  o4.x = f2bf_rne(acc.x); o4.y = f2bf_rne(acc.y);
  o4.z = f2bf_rne(acc.z); o4.w = f2bf_rne(acc.w);
  *(us4*)(out + (size_t)n * 512 + t * 4) = o4;
}

__global__ void k_aggb128(const u16* __restrict__ xin, const int* __restrict__ rowptr,
                          const int* __restrict__ csr_src, const float* __restrict__ csr_w,
                          u16* __restrict__ out) {
  int sub = threadIdx.x >> 5;
  int lane = threadIdx.x & 31;
  int n = blockIdx.x * 2 + sub;
  if (n >= NN) return;
  int beg = rowptr[n], end = rowptr[n + 1];
  float4 acc = {0.f, 0.f, 0.f, 0.f};
  for (int e = beg; e < end; ++e) {
    int s = csr_src[e];
    float w = csr_w[e];
    us4 h4 = *(const us4*)(xin + (size_t)s * 128 + lane * 4);
    acc.x += bf2f(h4.x) * w; acc.y += bf2f(h4.y) * w;
    acc.z += bf2f(h4.z) * w; acc.w += bf2f(h4.w) * w;
  }
  us4 o4;
  o4.x = f2bf_rne(acc.x); o4.y = f2bf_rne(acc.y);
  o4.z = f2bf_rne(acc.z); o4.w = f2bf_rne(acc.w);
  *(us4*)(out + (size_t)n * 128 + lane * 4) = o4;
}

// ------- bf16 MFMA GEMM: Ob[128x128 tiles] over A=[A0|A1], Wt[n][k] -------
// FOUT fixed 512. EPI: 0 = relu(v+bias); 1 = relu(BN(v+bias)); 2 = raw v.
// A+B staged via global_load_lds w16 (linear LDS, pre-swizzled global src);
// XOR-swizzled ds_read_b128 frags; LDS-restaged coalesced output.
template <int K, int W0, int EPI>
__global__ __launch_bounds__(256) void k_gemm(
    const u16* __restrict__ A0, const u16* __restrict__ A1,
    const u16* __restrict__ Wt, const float* __restrict__ bias,
    const float* __restrict__ gamma, const float* __restrict__ beta,
    const float* __restrict__ mean, const float* __restrict__ var,
    u16* __restrict__ Ob) {
  constexpr int FOUT = 512;
  __shared__ char LDSC[32768];
  u16* AS = (u16*)LDSC;            // 16 KB A tile [128 rows][64 k] (src-swizzled)
  u16* BS = (u16*)(LDSC + 16384);  // 16 KB B tile [128 cols][64 k] (src-swizzled)
  int tid = threadIdx.x;
  int wid = tid >> 6, l = tid & 63;
  int wr = wid >> 1, wc = wid & 1;

  // bijective XCD swizzle + quad mapping: 4 col-blocks of a row-panel adjacent
  int nwg = gridDim.x;  // 1564
  int q8 = nwg >> 3, r8 = nwg & 7;
  int xcd = blockIdx.x & 7, idx = blockIdx.x >> 3;
  int L = (xcd < r8 ? xcd * (q8 + 1) : r8 * (q8 + 1) + (xcd - r8) * q8) + idx;
  int n0 = (L >> 2) * 128, c0 = (L & 3) * 128;

  f32x4 acc[4][4] = {};

  // staging geometry: wave wid, instr j covers rows 32*wid+8j..+7 (1 KB each);
  // lane l -> row +(l>>3), 16B-chunk (l&7). LDS dest linear; global src chunk
  // pre-XORed so that swizzled ds_read sees the right data (involution).
  int srw = 32 * wid + (l >> 3);  // +8j
  int sch = l & 7;

  for (int k0 = 0; k0 < K; k0 += 64) {
    __syncthreads();  // previous compute done reading LDS
    {
      const u16* s; int rs; int seg;
      if (k0 < W0) { s = A0; rs = W0; seg = k0; }
      else         { s = A1; rs = K - W0; seg = k0 - W0; }
#pragma unroll
      for (int j = 0; j < 4; ++j) {
        int r = srw + 8 * j;
        int gr = n0 + r;
        if (gr >= NN) gr = NN - 1;
        int cc = sch ^ (r & 7);
        gload_lds16(s + (size_t)gr * rs + seg + cc * 8, AS + (32 * wid + 8 * j) * 64);
      }
#pragma unroll
      for (int j = 0; j < 4; ++j) {
        int r = srw + 8 * j;       // local col
        int cc = sch ^ (r & 7);
        gload_lds16(Wt + (size_t)(c0 + r) * K + k0 + cc * 8, BS + (32 * wid + 8 * j) * 64);
      }
    }
    __syncthreads();  // drains vmcnt(0): staged tiles visible

#pragma unroll
    for (int ks = 0; ks < 2; ++ks) {
      s16x8 b[4];
#pragma unroll
      for (int n = 0; n < 4; ++n) {
        int col = wc * 64 + n * 16 + (l & 15);
        int byte = (col * 128 + ks * 64 + ((l >> 4) << 4)) ^ ((col & 7) << 4);
        b[n] = *(const s16x8*)((const char*)BS + byte);
      }
#pragma unroll
      for (int m = 0; m < 4; ++m) {
        int row = wr * 64 + m * 16 + (l & 15);
        int byte = (row * 128 + ks * 64 + ((l >> 4) << 4)) ^ ((row & 7) << 4);
        s16x8 a = *(const s16x8*)((const char*)AS + byte);
#pragma unroll
        for (int n = 0; n < 4; ++n)
          acc[m][n] = __builtin_amdgcn_mfma_f32_16x16x32_bf16(a, b[n], acc[m][n], 0, 0, 0);
      }
    }
  }

  // ---- epilogue: EPI -> LDS restage (swizzled) -> coalesced 16B stores ----
  __syncthreads();
  u16* OS = (u16*)LDSC;  // [128][128] bf16 = 32 KB
#pragma unroll
  for (int n = 0; n < 4; ++n) {
    int colL = wc * 64 + n * 16 + (l & 15);
    int col = c0 + colL;
    float bs = (EPI == 2) ? 0.f : bias[col];
    float sc = 1.f, sf = 0.f;
    if (EPI == 1) {
      sc = rsqrtf(var[col] + BN_EPS) * gamma[col];
      sf = beta[col] - mean[col] * sc;
    }
#pragma unroll
    for (int m = 0; m < 4; ++m) {
      int rowL0 = wr * 64 + m * 16 + ((l >> 4) << 2);
#pragma unroll
      for (int r = 0; r < 4; ++r) {
        float v = acc[m][n][r];
        if (EPI != 2) {
          v += bs;
          if (EPI == 1) v = v * sc + sf;
          v = fmaxf(v, 0.f);
        }
        int rowL = rowL0 + r;
        int byte = (rowL * 256 + colL * 2) ^ ((rowL & 7) << 4);
        *(u16*)((char*)OS + byte) = f2bf_rne(v);
      }
    }
  }
  __syncthreads();
#pragma unroll
  for (int i = 0; i < 8; ++i) {
    int chunk = i * 256 + tid;      // 0..2047
    int rowL = chunk >> 4;          // 16 x 16B chunks per 256B row
    int cs = (chunk & 15) * 8;      // col start (u16 units)
    int rr = n0 + rowL;
    if (rr < NN) {
      int byte = (rowL * 256 + cs * 2) ^ ((rowL & 7) << 4);
      *(uint4*)(Ob + (size_t)rr * FOUT + c0 + cs) = *(const uint4*)((const char*)OS + byte);
    }
  }
}

// ------- L3 combine: h3 = relu(agg256(P) + Q + bl3), P|Q packed [N,512] -------
__global__ void k_aggcomb(const u16* __restrict__ PQ, const int* __restrict__ rowptr,
                          const int* __restrict__ csr_src, const float* __restrict__ csr_w,
                          const float* __restrict__ bl3, float* __restrict__ h3) {
  int sub = threadIdx.x >> 6;
  int lane = threadIdx.x & 63;
  int n = blockIdx.x * 2 + sub;
  if (n >= NN) return;
  int beg = rowptr[n], end = rowptr[n + 1];
  float4 acc = {0.f, 0.f, 0.f, 0.f};
  for (int e = beg; e < end; ++e) {
    int s = csr_src[e];
    float w = csr_w[e];
    us4 h4 = *(const us4*)(PQ + (size_t)s * 512 + lane * 4);  // P region: cols 0..255
    acc.x += bf2f(h4.x) * w; acc.y += bf2f(h4.y) * w;
    acc.z += bf2f(h4.z) * w; acc.w += bf2f(h4.w) * w;
  }
  us4 qv = *(const us4*)(PQ + (size_t)n * 512 + 256 + lane * 4);
  float4 bb = *(const float4*)(bl3 + lane * 4);
  float4 o;
  o.x = fmaxf(acc.x + bf2f(qv.x) + bb.x, 0.f);
  o.y = fmaxf(acc.y + bf2f(qv.y) + bb.y, 0.f);
  o.z = fmaxf(acc.z + bf2f(qv.z) + bb.z, 0.f);
  o.w = fmaxf(acc.w + bf2f(qv.w) + bb.w, 0.f);
  *(float4*)(h3 + (size_t)n * 256 + lane * 4) = o;
}

// ---------------- pooling + MLP ----------------
__global__ void k_counts(const int* __restrict__ batch, float* __restrict__ cnt) {
  int g = threadIdx.x;  // 64 threads
  int lo = 0, hi = NN;
  while (lo < hi) { int m = (lo + hi) >> 1; if (batch[m] < g) lo = m + 1; else hi = m; }
  int a = lo;
  lo = 0; hi = NN;
  int g1 = g + 1;
  while (lo < hi) { int m = (lo + hi) >> 1; if (batch[m] < g1) lo = m + 1; else hi = m; }
  cnt[g] = (float)(lo - a);
}

__global__ void k_pool(const float* __restrict__ h, const int* __restrict__ batch,
                       float* __restrict__ sums) {
  int f = threadIdx.x;  // 256 features
  int n0 = blockIdx.x * 128;
  int n1 = n0 + 128; if (n1 > NN) n1 = NN;
  float acc = 0.f;
  int cur = clampi(batch[n0], 0, NG - 1);
  for (int n = n0; n < n1; ++n) {
    int g = clampi(batch[n], 0, NG - 1);
    if (g != cur) {
      atomicAdd(&sums[(size_t)cur * 256 + f], acc);
      acc = 0.f;
      cur = g;
    }
    acc += h[(size_t)n * 256 + f];
  }
  atomicAdd(&sums[(size_t)cur * 256 + f], acc);
}

__global__ void k_mlp(const float* __restrict__ sums, const float* __restrict__ cnt,
                      const float* __restrict__ W4, const float* __restrict__ b4,
                      const float* __restrict__ W5, const float* __restrict__ b5,
                      float* __restrict__ out) {
  __shared__ float g[256];
  int b = blockIdx.x, t = threadIdx.x;  // 64 threads
  float inv = 1.f / fmaxf(cnt[b], 1.f);
#pragma unroll
  for (int q = 0; q < 4; ++q) g[q * 64 + t] = sums[(size_t)b * 256 + q * 64 + t] * inv;
  __syncthreads();
  float acc = 0.f;
#pragma unroll 8
  for (int k = 0; k < 256; ++k) acc += g[k] * W4[k * 64 + t];
  float a = fmaxf(acc + b4[t], 0.f) * W5[t];
  for (int off = 32; off; off >>= 1) a += __shfl_down(a, off, 64);
  if (t == 0) out[b] = fmaxf(a + b5[0], 0.f);
}

// ---------------- launcher ----------------
extern "C" void kernel_launch(void* const* d_in, const int* in_sizes, int n_in,
                              void* d_out, int out_size, void* d_ws, size_t ws_size,
                              hipStream_t stream) {
  const float* x     = (const float*)d_in[0];
  const int*   eidx  = (const int*)d_in[1];
  const float* ew    = (const float*)d_in[2];
  const int*   batch = (const int*)d_in[3];
  const float* Wl1 = (const float*)d_in[4];
  const float* bl1 = (const float*)d_in[5];
  const float* Wr1 = (const float*)d_in[6];
  const float* Wl2 = (const float*)d_in[7];
  const float* bl2 = (const float*)d_in[8];
  const float* Wr2 = (const float*)d_in[9];
  const float* Wl3 = (const float*)d_in[10];
  const float* bl3 = (const float*)d_in[11];
  const float* Wr3 = (const float*)d_in[12];
  const float* gamma = (const float*)d_in[13];
  const float* beta  = (const float*)d_in[14];
  const float* mean  = (const float*)d_in[15];
  const float* var   = (const float*)d_in[16];
  const float* W4 = (const float*)d_in[17];
  const float* b4 = (const float*)d_in[18];
  const float* W5 = (const float*)d_in[19];
  const float* b5 = (const float*)d_in[20];

  const int* src = eidx;
  const int* dst = eidx + NE;

  // ---- workspace layout (~176 MB; ws_size known >= 313 MB) ----
  const size_t PH = (size_t)NN * 512 * 2;  // 51.2 MB bf16 plane
  char* w = (char*)d_ws;
  u16* X1 = (u16*)w; w += PH;              // h1 bf16; later h3 fp32 [N,256]
  u16* X2 = (u16*)w; w += PH;              // h2 bf16
  u16* Ag = (u16*)w; w += PH;              // agg stream / PQ plane
  u16* Xb = (u16*)w; w += (size_t)NN * 128 * 2;
  u16* Wt1 = (u16*)w; w += (size_t)512 * 256 * 2;
  u16* Wt2 = (u16*)w; w += (size_t)512 * 1024 * 2;
  u16* Wt3 = (u16*)w; w += (size_t)512 * 512 * 2;
  int*   csr_src = (int*)w;   w += (size_t)NE * 4;
  float* csr_w   = (float*)w; w += (size_t)NE * 4;
  int*   rowptr  = (int*)w;   w += ((size_t)NN + 4) * 4;
  int*   cursor  = (int*)w;   w += (size_t)NN * 4;
  int*   aux     = (int*)w;   w += 1024;
  float* sums    = (float*)w; w += (size_t)NG * 256 * 4;
  float* cnt     = (float*)w; w += 1024;
  float* h3 = (float*)X1;  // [N,256] fp32 reuses X1 after h1 dead

  int nblk = (NN + 255) / 256;  // 196

  // CSR build + input conversion + weight prep
  k_zero32<<<nblk, 256, 0, stream>>>((u32*)cursor, NN);
  k_count<<<(NE + 255) / 256, 256, 0, stream>>>(dst, cursor);
  k_scan_block<<<nblk, 256, 0, stream>>>(cursor, rowptr, aux);
  k_scan_aux<<<1, 256, 0, stream>>>(aux, nblk);
  k_fix<<<nblk, 256, 0, stream>>>(rowptr, aux, cursor);
  k_fill<<<(NE + 255) / 256, 256, 0, stream>>>(src, dst, ew, cursor, csr_src, csr_w);
  k_cvt_x<<<(NN * 128 / 8 + 255) / 256, 256, 0, stream>>>(x, Xb);
  k_wt<<<dim3(512, 1), 256, 0, stream>>>(Wl1, Wr1, 128, 512, Wt1);
  k_wt<<<dim3(512, 4), 256, 0, stream>>>(Wl2, Wr2, 512, 512, Wt2);
  k_wtn<<<dim3(512, 2), 256, 0, stream>>>(Wl3, Wr3, 512, 256, Wt3);

  const int NWG = 391 * 4;  // 1564 (128x128 tiles over [50048 x 512])

  // Layer 1: agg(x) -> Ag; h1 = relu([Ag|Xb]@Wt1 + bl1)
  k_aggb128<<<(NN + 1) / 2, 64, 0, stream>>>(Xb, rowptr, csr_src, csr_w, Ag);
  k_gemm<256, 128, 0><<<NWG, 256, 0, stream>>>(
      Ag, Xb, Wt1, bl1, nullptr, nullptr, nullptr, nullptr, X1);

  // Layer 2: agg(h1) -> Ag; h2 = relu(BN([Ag|h1]@Wt2 + bl2))
  k_aggb512<<<NN, 128, 0, stream>>>(X1, rowptr, csr_src, csr_w, Ag);
  k_gemm<1024, 512, 1><<<NWG, 256, 0, stream>>>(
      Ag, X1, Wt2, bl2, gamma, beta, mean, var, X2);

  // Layer 3: PQ = h2 @ [Wl3|Wr3] (raw); h3 = relu(agg256(P) + Q + bl3)
  k_gemm<512, 512, 2><<<NWG, 256, 0, stream>>>(
      X2, X2, Wt3, nullptr, nullptr, nullptr, nullptr, nullptr, Ag);
  k_aggcomb<<<(NN + 1) / 2, 128, 0, stream>>>(Ag, rowptr, csr_src, csr_w, bl3, h3);

  // pool + MLP
  k_zero32<<<(NG * 256 + 255) / 256, 256, 0, stream>>>((u32*)sums, NG * 256);
  k_pool<<<(NN + 127) / 128, 256, 0, stream>>>(h3, batch, sums);
  k_counts<<<1, 64, 0, stream>>>(batch, cnt);
  k_mlp<<<NG, 64, 0, stream>>>(sums, cnt, W4, b4, W5, b5, (float*)d_out);
}

// Round 11
// 508.318 us; speedup vs baseline: 3.8517x; 1.1614x over previous
//
#include <hip/hip_runtime.h>

#define NN 50000
#define NE 800000
#define NG 64
#define BN_EPS 1e-5f

typedef unsigned short u16;
typedef unsigned int u32;
typedef unsigned char u8;
struct alignas(8) us4 { u16 x, y, z, w; };
typedef short s16x8 __attribute__((ext_vector_type(8)));
typedef float f32x4 __attribute__((ext_vector_type(4)));

__device__ inline float bf2f(u16 h) { return __uint_as_float((u32)h << 16); }
__device__ inline u16 f2bf_rne(float f) {
  u32 u = __float_as_uint(f);
  return (u16)((u + 0x7fff + ((u >> 16) & 1)) >> 16);
}
__device__ inline int clampi(int v, int lo, int hi) {
  return v < lo ? lo : (v > hi ? hi : v);
}
// async global->LDS DMA, 16B per lane; LDS dest is wave-uniform base
__device__ inline void gload_lds16(const void* g, void* l) {
  __builtin_amdgcn_global_load_lds(
      (const __attribute__((address_space(1))) u32*)g,
      (__attribute__((address_space(3))) u32*)l, 16, 0, 0);
}
// fp8 e4m3 (OCP on gfx950) HW converts
__device__ inline float4 fp8x4f(u32 q) {
  float4 r;
  r.x = __builtin_amdgcn_cvt_f32_fp8(q, 0);
  r.y = __builtin_amdgcn_cvt_f32_fp8(q, 1);
  r.z = __builtin_amdgcn_cvt_f32_fp8(q, 2);
  r.w = __builtin_amdgcn_cvt_f32_fp8(q, 3);
  return r;
}
__device__ inline u8 f2fp8(float v) {
  return (u8)(__builtin_amdgcn_cvt_pk_fp8_f32(v, 0.f, 0u, false) & 0xffu);
}

// ---------------- utility ----------------
__global__ void k_zero32(u32* __restrict__ p, int n) {
  int i = blockIdx.x * 256 + threadIdx.x;
  if (i < n) p[i] = 0u;
}

// fp32 [N*128] -> bf16 plane + fp8 plane
__global__ void k_cvt_x(const float* __restrict__ x, u16* __restrict__ xb,
                        u8* __restrict__ xf8) {
  int i = blockIdx.x * 256 + threadIdx.x;
  if (i >= NN * 128 / 8) return;
  size_t o = (size_t)i * 8;
  float4 a = *(const float4*)(x + o);
  float4 b = *(const float4*)(x + o + 4);
  us4 h0, h1;
  h0.x = f2bf_rne(a.x); h0.y = f2bf_rne(a.y); h0.z = f2bf_rne(a.z); h0.w = f2bf_rne(a.w);
  h1.x = f2bf_rne(b.x); h1.y = f2bf_rne(b.y); h1.z = f2bf_rne(b.z); h1.w = f2bf_rne(b.w);
  *(us4*)(xb + o) = h0;
  *(us4*)(xb + o + 4) = h1;
  u32 p0 = __builtin_amdgcn_cvt_pk_fp8_f32(a.x, a.y, 0u, false);
  p0 = __builtin_amdgcn_cvt_pk_fp8_f32(a.z, a.w, p0, true);
  u32 p1 = __builtin_amdgcn_cvt_pk_fp8_f32(b.x, b.y, 0u, false);
  p1 = __builtin_amdgcn_cvt_pk_fp8_f32(b.z, b.w, p1, true);
  *(uint2*)(xf8 + o) = make_uint2(p0, p1);
}

// ---------------- CSR build (proven) ----------------
__global__ void k_count(const int* __restrict__ dst, int* __restrict__ deg) {
  int e = blockIdx.x * 256 + threadIdx.x;
  if (e < NE) atomicAdd(&deg[clampi(dst[e], 0, NN - 1)], 1);
}

__global__ void k_scan_block(const int* __restrict__ deg, int* __restrict__ excl,
                             int* __restrict__ aux) {
  __shared__ int s[256];
  int t = threadIdx.x;
  int idx = blockIdx.x * 256 + t;
  int v = (idx < NN) ? deg[idx] : 0;
  s[t] = v;
  __syncthreads();
  for (int off = 1; off < 256; off <<= 1) {
    int x = (t >= off) ? s[t - off] : 0;
    __syncthreads();
    s[t] += x;
    __syncthreads();
  }
  if (idx < NN) excl[idx] = s[t] - v;
  if (t == 255) aux[blockIdx.x] = s[255];
}

__global__ void k_scan_aux(int* aux, int nblk) {
  __shared__ int s[256];
  int t = threadIdx.x;
  int v = (t < nblk) ? aux[t] : 0;
  s[t] = v;
  __syncthreads();
  for (int off = 1; off < 256; off <<= 1) {
    int x = (t >= off) ? s[t - off] : 0;
    __syncthreads();
    s[t] += x;
    __syncthreads();
  }
  if (t < nblk) aux[t] = s[t] - v;
}

__global__ void k_fix(int* __restrict__ rowptr, const int* __restrict__ aux,
                      int* __restrict__ cursor) {
  int idx = blockIdx.x * 256 + threadIdx.x;
  if (idx < NN) {
    int v = rowptr[idx] + aux[blockIdx.x];
    rowptr[idx] = v;
    cursor[idx] = v;
  }
  if (idx == 0) rowptr[NN] = NE;
}

__global__ void k_fill(const int* __restrict__ src, const int* __restrict__ dst,
                       const float* __restrict__ ew, int* __restrict__ cursor,
                       int* __restrict__ csr_src, float* __restrict__ csr_w) {
  int e = blockIdx.x * 256 + threadIdx.x;
  if (e < NE) {
    int d = clampi(dst[e], 0, NN - 1);
    int p = atomicAdd(&cursor[d], 1);
    p = clampi(p, 0, NE - 1);
    csr_src[p] = clampi(src[e], 0, NN - 1);
    csr_w[p] = ew[e];
  }
}

// --------- weight prep: Wt[n][k] = [Wl;Wr] concat along k (bf16) ---------
__global__ void k_wt(const float* __restrict__ Wl, const float* __restrict__ Wr,
                     int FIN, int FOUT, u16* __restrict__ t16) {
  int k = blockIdx.y * 256 + threadIdx.x;
  int n = blockIdx.x;
  int K = 2 * FIN;
  if (k >= K) return;
  float v = (k < FIN) ? Wl[(size_t)k * FOUT + n] : Wr[(size_t)(k - FIN) * FOUT + n];
  t16[(size_t)n * K + k] = f2bf_rne(v);
}

// --------- weight prep: Wt[n][k] = [Wl|Wr] concat along n (bf16) ---------
__global__ void k_wtn(const float* __restrict__ Wl, const float* __restrict__ Wr,
                      int Kdim, int half, u16* __restrict__ t16) {
  int k = blockIdx.y * 256 + threadIdx.x;
  int n = blockIdx.x;
  if (k >= Kdim) return;
  float v = (n < half) ? Wl[(size_t)k * half + n] : Wr[(size_t)k * half + (n - half)];
  t16[(size_t)n * Kdim + k] = f2bf_rne(v);
}

// ---------------- aggregation (fp8 gather over CSR, bf16 out) ----------------
__global__ void k_aggf512(const u8* __restrict__ xf8, const int* __restrict__ rowptr,
                          const int* __restrict__ csr_src, const float* __restrict__ csr_w,
                          u16* __restrict__ out) {
  int n = blockIdx.x;
  int t = threadIdx.x;  // 0..127
  int beg = rowptr[n], end = rowptr[n + 1];
  float4 acc = {0.f, 0.f, 0.f, 0.f};
  int e = beg;
  for (; e + 2 <= end; e += 2) {
    int s0 = csr_src[e], s1 = csr_src[e + 1];
    float w0 = csr_w[e], w1 = csr_w[e + 1];
    u32 q0 = *(const u32*)(xf8 + (size_t)s0 * 512 + t * 4);
    u32 q1 = *(const u32*)(xf8 + (size_t)s1 * 512 + t * 4);
    float4 v0 = fp8x4f(q0), v1 = fp8x4f(q1);
    acc.x += v0.x * w0 + v1.x * w1;
    acc.y += v0.y * w0 + v1.y * w1;
    acc.z += v0.z * w0 + v1.z * w1;
    acc.w += v0.w * w0 + v1.w * w1;
  }
  if (e < end) {
    int s0 = csr_src[e];
    float w0 = csr_w[e];
    float4 v0 = fp8x4f(*(const u32*)(xf8 + (size_t)s0 * 512 + t * 4));
    acc.x += v0.x * w0; acc.y += v0.y * w0;
    acc.z += v0.z * w0; acc.w += v0.w * w0;
  }
  us4 o4;
  o4.x = f2bf_rne(acc.x); o4.y = f2bf_rne(acc.y);
  o4.z = f2bf_rne(acc.z); o4.w = f2bf_rne(acc.w);
  *(us4*)(out + (size_t)n * 512 + t * 4) = o4;
}

__global__ void k_aggf128(const u8* __restrict__ xf8, const int* __restrict__ rowptr,
                          const int* __restrict__ csr_src, const float* __restrict__ csr_w,
                          u16* __restrict__ out) {
  int sub = threadIdx.x >> 5;
  int lane = threadIdx.x & 31;
  int n = blockIdx.x * 2 + sub;
  if (n >= NN) return;
  int beg = rowptr[n], end = rowptr[n + 1];
  float4 acc = {0.f, 0.f, 0.f, 0.f};
  int e = beg;
  for (; e + 2 <= end; e += 2) {
    int s0 = csr_src[e], s1 = csr_src[e + 1];
    float w0 = csr_w[e], w1 = csr_w[e + 1];
    float4 v0 = fp8x4f(*(const u32*)(xf8 + (size_t)s0 * 128 + lane * 4));
    float4 v1 = fp8x4f(*(const u32*)(xf8 + (size_t)s1 * 128 + lane * 4));
    acc.x += v0.x * w0 + v1.x * w1;
    acc.y += v0.y * w0 + v1.y * w1;
    acc.z += v0.z * w0 + v1.z * w1;
    acc.w += v0.w * w0 + v1.w * w1;
  }
  if (e < end) {
    int s0 = csr_src[e];
    float w0 = csr_w[e];
    float4 v0 = fp8x4f(*(const u32*)(xf8 + (size_t)s0 * 128 + lane * 4));
    acc.x += v0.x * w0; acc.y += v0.y * w0;
    acc.z += v0.z * w0; acc.w += v0.w * w0;
  }
  us4 o4;
  o4.x = f2bf_rne(acc.x); o4.y = f2bf_rne(acc.y);
  o4.z = f2bf_rne(acc.z); o4.w = f2bf_rne(acc.w);
  *(us4*)(out + (size_t)n * 128 + lane * 4) = o4;
}

// ------- bf16 MFMA GEMM: Ob[128x128 tiles] over A=[A0|A1], Wt[n][k] -------
// FOUT fixed 512. EPI: 0 = relu(v+bias); 1 = relu(BN(v+bias)); 2 = raw v.
// F8: 0 none; 1 full fp8 plane (stride 512); 2 fp8 of cols<256 (stride 256).
template <int K, int W0, int EPI, int F8>
__global__ __launch_bounds__(256) void k_gemm(
    const u16* __restrict__ A0, const u16* __restrict__ A1,
    const u16* __restrict__ Wt, const float* __restrict__ bias,
    const float* __restrict__ gamma, const float* __restrict__ beta,
    const float* __restrict__ mean, const float* __restrict__ var,
    u16* __restrict__ Ob, u8* __restrict__ Of8) {
  constexpr int FOUT = 512;
  __shared__ char LDSC[32768];
  u16* AS = (u16*)LDSC;            // 16 KB A tile (src-swizzled)
  u16* BS = (u16*)(LDSC + 16384);  // 16 KB B tile (src-swizzled)
  int tid = threadIdx.x;
  int wid = tid >> 6, l = tid & 63;
  int wr = wid >> 1, wc = wid & 1;

  // bijective XCD swizzle + quad mapping
  int nwg = gridDim.x;  // 1564
  int q8 = nwg >> 3, r8 = nwg & 7;
  int xcd = blockIdx.x & 7, idx = blockIdx.x >> 3;
  int L = (xcd < r8 ? xcd * (q8 + 1) : r8 * (q8 + 1) + (xcd - r8) * q8) + idx;
  int n0 = (L >> 2) * 128, c0 = (L & 3) * 128;

  f32x4 acc[4][4] = {};

  int srw = 32 * wid + (l >> 3);  // staged row (+8j)
  int sch = l & 7;                // 16B chunk

  for (int k0 = 0; k0 < K; k0 += 64) {
    __syncthreads();
    {
      const u16* s; int rs; int seg;
      if (k0 < W0) { s = A0; rs = W0; seg = k0; }
      else         { s = A1; rs = K - W0; seg = k0 - W0; }
#pragma unroll
      for (int j = 0; j < 4; ++j) {
        int r = srw + 8 * j;
        int gr = n0 + r;
        if (gr >= NN) gr = NN - 1;
        int cc = sch ^ (r & 7);
        gload_lds16(s + (size_t)gr * rs + seg + cc * 8, AS + (32 * wid + 8 * j) * 64);
      }
#pragma unroll
      for (int j = 0; j < 4; ++j) {
        int r = srw + 8 * j;
        int cc = sch ^ (r & 7);
        gload_lds16(Wt + (size_t)(c0 + r) * K + k0 + cc * 8, BS + (32 * wid + 8 * j) * 64);
      }
    }
    __syncthreads();

#pragma unroll
    for (int ks = 0; ks < 2; ++ks) {
      s16x8 b[4];
#pragma unroll
      for (int n = 0; n < 4; ++n) {
        int col = wc * 64 + n * 16 + (l & 15);
        int byte = (col * 128 + ks * 64 + ((l >> 4) << 4)) ^ ((col & 7) << 4);
        b[n] = *(const s16x8*)((const char*)BS + byte);
      }
#pragma unroll
      for (int m = 0; m < 4; ++m) {
        int row = wr * 64 + m * 16 + (l & 15);
        int byte = (row * 128 + ks * 64 + ((l >> 4) << 4)) ^ ((row & 7) << 4);
        s16x8 a = *(const s16x8*)((const char*)AS + byte);
#pragma unroll
        for (int n = 0; n < 4; ++n)
          acc[m][n] = __builtin_amdgcn_mfma_f32_16x16x32_bf16(a, b[n], acc[m][n], 0, 0, 0);
      }
    }
  }

  // ---- epilogue pass 1: EPI -> LDS restage (swizzled) -> coalesced bf16 ----
  __syncthreads();
  u16* OS = (u16*)LDSC;  // [128][128] bf16 = 32 KB
#pragma unroll
  for (int n = 0; n < 4; ++n) {
    int colL = wc * 64 + n * 16 + (l & 15);
    int col = c0 + colL;
    float bs = (EPI == 2) ? 0.f : bias[col];
    float sc = 1.f, sf = 0.f;
    if (EPI == 1) {
      sc = rsqrtf(var[col] + BN_EPS) * gamma[col];
      sf = beta[col] - mean[col] * sc;
    }
#pragma unroll
    for (int m = 0; m < 4; ++m) {
      int rowL0 = wr * 64 + m * 16 + ((l >> 4) << 2);
#pragma unroll
      for (int r = 0; r < 4; ++r) {
        float v = acc[m][n][r];
        if (EPI != 2) {
          v += bs;
          if (EPI == 1) v = v * sc + sf;
          v = fmaxf(v, 0.f);
        }
        acc[m][n][r] = v;  // keep post-EPI value for fp8 pass
        int rowL = rowL0 + r;
        int byte = (rowL * 256 + colL * 2) ^ ((rowL & 7) << 4);
        *(u16*)((char*)OS + byte) = f2bf_rne(v);
      }
    }
  }
  __syncthreads();
#pragma unroll
  for (int i = 0; i < 8; ++i) {
    int chunk = i * 256 + tid;      // 0..2047
    int rowL = chunk >> 4;
    int cs = (chunk & 15) * 8;
    int rr = n0 + rowL;
    if (rr < NN) {
      int byte = (rowL * 256 + cs * 2) ^ ((rowL & 7) << 4);
      *(uint4*)(Ob + (size_t)rr * FOUT + c0 + cs) = *(const uint4*)((const char*)OS + byte);
    }
  }

  // ---- epilogue pass 2: fp8 plane ----
  if constexpr (F8 > 0) {
    constexpr int F8S = (F8 == 2) ? 256 : 512;
    if (F8 == 2 && c0 >= 256) return;  // block-uniform: no barrier divergence
    __syncthreads();
    u8* O8 = (u8*)LDSC;  // [128][128] u8 = 16 KB
#pragma unroll
    for (int n = 0; n < 4; ++n) {
      int colL = wc * 64 + n * 16 + (l & 15);
#pragma unroll
      for (int m = 0; m < 4; ++m) {
        int rowL0 = wr * 64 + m * 16 + ((l >> 4) << 2);
#pragma unroll
        for (int r = 0; r < 4; ++r) {
          int rowL = rowL0 + r;
          int byte = (rowL * 128 + colL) ^ ((rowL & 7) << 4);
          O8[byte] = f2fp8(acc[m][n][r]);
        }
      }
    }
    __syncthreads();
#pragma unroll
    for (int i = 0; i < 4; ++i) {
      int chunk = i * 256 + tid;   // 0..1023 chunks of 16B
      int rowL = chunk >> 3;
      int cs = (chunk & 7) * 16;
      int rr = n0 + rowL;
      if (rr < NN) {
        int byte = (rowL * 128 + cs) ^ ((rowL & 7) << 4);
        *(uint4*)(Of8 + (size_t)rr * F8S + c0 + cs) = *(const uint4*)((const char*)O8 + byte);
      }
    }
  }
}

// ------- L3 combine: h3 = relu(agg256(Pf8) + Q + bl3); Q = PQ[:,256:512] -------
__global__ void k_aggcomb(const u8* __restrict__ Pf8, const u16* __restrict__ PQ,
                          const int* __restrict__ rowptr, const int* __restrict__ csr_src,
                          const float* __restrict__ csr_w,
                          const float* __restrict__ bl3, float* __restrict__ h3) {
  int sub = threadIdx.x >> 6;
  int lane = threadIdx.x & 63;
  int n = blockIdx.x * 2 + sub;
  if (n >= NN) return;
  int beg = rowptr[n], end = rowptr[n + 1];
  float4 acc = {0.f, 0.f, 0.f, 0.f};
  int e = beg;
  for (; e + 2 <= end; e += 2) {
    int s0 = csr_src[e], s1 = csr_src[e + 1];
    float w0 = csr_w[e], w1 = csr_w[e + 1];
    float4 v0 = fp8x4f(*(const u32*)(Pf8 + (size_t)s0 * 256 + lane * 4));
    float4 v1 = fp8x4f(*(const u32*)(Pf8 + (size_t)s1 * 256 + lane * 4));
    acc.x += v0.x * w0 + v1.x * w1;
    acc.y += v0.y * w0 + v1.y * w1;
    acc.z += v0.z * w0 + v1.z * w1;
    acc.w += v0.w * w0 + v1.w * w1;
  }
  if (e < end) {
    int s0 = csr_src[e];
    float w0 = csr_w[e];
    float4 v0 = fp8x4f(*(const u32*)(Pf8 + (size_t)s0 * 256 + lane * 4));
    acc.x += v0.x * w0; acc.y += v0.y * w0;
    acc.z += v0.z * w0; acc.w += v0.w * w0;
  }
  us4 qv = *(const us4*)(PQ + (size_t)n * 512 + 256 + lane * 4);
  float4 bb = *(const float4*)(bl3 + lane * 4);
  float4 o;
  o.x = fmaxf(acc.x + bf2f(qv.x) + bb.x, 0.f);
  o.y = fmaxf(acc.y + bf2f(qv.y) + bb.y, 0.f);
  o.z = fmaxf(acc.z + bf2f(qv.z) + bb.z, 0.f);
  o.w = fmaxf(acc.w + bf2f(qv.w) + bb.w, 0.f);
  *(float4*)(h3 + (size_t)n * 256 + lane * 4) = o;
}

// ---------------- pooling + MLP ----------------
__global__ void k_counts(const int* __restrict__ batch, float* __restrict__ cnt) {
  int g = threadIdx.x;  // 64 threads
  int lo = 0, hi = NN;
  while (lo < hi) { int m = (lo + hi) >> 1; if (batch[m] < g) lo = m + 1; else hi = m; }
  int a = lo;
  lo = 0; hi = NN;
  int g1 = g + 1;
  while (lo < hi) { int m = (lo + hi) >> 1; if (batch[m] < g1) lo = m + 1; else hi = m; }
  cnt[g] = (float)(lo - a);
}

__global__ void k_pool(const float* __restrict__ h, const int* __restrict__ batch,
                       float* __restrict__ sums) {
  int f = threadIdx.x;  // 256 features
  int n0 = blockIdx.x * 128;
  int n1 = n0 + 128; if (n1 > NN) n1 = NN;
  float acc = 0.f;
  int cur = clampi(batch[n0], 0, NG - 1);
  for (int n = n0; n < n1; ++n) {
    int g = clampi(batch[n], 0, NG - 1);
    if (g != cur) {
      atomicAdd(&sums[(size_t)cur * 256 + f], acc);
      acc = 0.f;
      cur = g;
    }
    acc += h[(size_t)n * 256 + f];
  }
  atomicAdd(&sums[(size_t)cur * 256 + f], acc);
}

__global__ void k_mlp(const float* __restrict__ sums, const float* __restrict__ cnt,
                      const float* __restrict__ W4, const float* __restrict__ b4,
                      const float* __restrict__ W5, const float* __restrict__ b5,
                      float* __restrict__ out) {
  __shared__ float g[256];
  int b = blockIdx.x, t = threadIdx.x;  // 64 threads
  float inv = 1.f / fmaxf(cnt[b], 1.f);
#pragma unroll
  for (int q = 0; q < 4; ++q) g[q * 64 + t] = sums[(size_t)b * 256 + q * 64 + t] * inv;
  __syncthreads();
  float acc = 0.f;
#pragma unroll 8
  for (int k = 0; k < 256; ++k) acc += g[k] * W4[k * 64 + t];
  float a = fmaxf(acc + b4[t], 0.f) * W5[t];
  for (int off = 32; off; off >>= 1) a += __shfl_down(a, off, 64);
  if (t == 0) out[b] = fmaxf(a + b5[0], 0.f);
}

// ---------------- launcher ----------------
extern "C" void kernel_launch(void* const* d_in, const int* in_sizes, int n_in,
                              void* d_out, int out_size, void* d_ws, size_t ws_size,
                              hipStream_t stream) {
  const float* x     = (const float*)d_in[0];
  const int*   eidx  = (const int*)d_in[1];
  const float* ew    = (const float*)d_in[2];
  const int*   batch = (const int*)d_in[3];
  const float* Wl1 = (const float*)d_in[4];
  const float* bl1 = (const float*)d_in[5];
  const float* Wr1 = (const float*)d_in[6];
  const float* Wl2 = (const float*)d_in[7];
  const float* bl2 = (const float*)d_in[8];
  const float* Wr2 = (const float*)d_in[9];
  const float* Wl3 = (const float*)d_in[10];
  const float* bl3 = (const float*)d_in[11];
  const float* Wr3 = (const float*)d_in[12];
  const float* gamma = (const float*)d_in[13];
  const float* beta  = (const float*)d_in[14];
  const float* mean  = (const float*)d_in[15];
  const float* var   = (const float*)d_in[16];
  const float* W4 = (const float*)d_in[17];
  const float* b4 = (const float*)d_in[18];
  const float* W5 = (const float*)d_in[19];
  const float* b5 = (const float*)d_in[20];

  const int* src = eidx;
  const int* dst = eidx + NE;

  // ---- workspace layout (~220 MB; ws_size known >= 313 MB) ----
  const size_t PH = (size_t)NN * 512 * 2;  // 51.2 MB bf16 plane
  char* w = (char*)d_ws;
  u16* X1 = (u16*)w; w += PH;              // h1 bf16; later h3 fp32 [N,256]
  u16* X2 = (u16*)w; w += PH;              // h2 bf16
  u16* Ag = (u16*)w; w += PH;              // agg stream / PQ plane
  u16* Xb = (u16*)w; w += (size_t)NN * 128 * 2;
  u8*  Xf8  = (u8*)w; w += (size_t)NN * 128;
  u8*  X1f8 = (u8*)w; w += (size_t)NN * 512;
  u8*  Pf8  = (u8*)w; w += (size_t)NN * 256;
  u16* Wt1 = (u16*)w; w += (size_t)512 * 256 * 2;
  u16* Wt2 = (u16*)w; w += (size_t)512 * 1024 * 2;
  u16* Wt3 = (u16*)w; w += (size_t)512 * 512 * 2;
  int*   csr_src = (int*)w;   w += (size_t)NE * 4;
  float* csr_w   = (float*)w; w += (size_t)NE * 4;
  int*   rowptr  = (int*)w;   w += ((size_t)NN + 4) * 4;
  int*   cursor  = (int*)w;   w += (size_t)NN * 4;
  int*   aux     = (int*)w;   w += 1024;
  float* sums    = (float*)w; w += (size_t)NG * 256 * 4;
  float* cnt     = (float*)w; w += 1024;
  float* h3 = (float*)X1;  // [N,256] fp32 reuses X1 after h1 dead

  int nblk = (NN + 255) / 256;  // 196

  // CSR build + input conversion + weight prep
  k_zero32<<<nblk, 256, 0, stream>>>((u32*)cursor, NN);
  k_count<<<(NE + 255) / 256, 256, 0, stream>>>(dst, cursor);
  k_scan_block<<<nblk, 256, 0, stream>>>(cursor, rowptr, aux);
  k_scan_aux<<<1, 256, 0, stream>>>(aux, nblk);
  k_fix<<<nblk, 256, 0, stream>>>(rowptr, aux, cursor);
  k_fill<<<(NE + 255) / 256, 256, 0, stream>>>(src, dst, ew, cursor, csr_src, csr_w);
  k_cvt_x<<<(NN * 128 / 8 + 255) / 256, 256, 0, stream>>>(x, Xb, Xf8);
  k_wt<<<dim3(512, 1), 256, 0, stream>>>(Wl1, Wr1, 128, 512, Wt1);
  k_wt<<<dim3(512, 4), 256, 0, stream>>>(Wl2, Wr2, 512, 512, Wt2);
  k_wtn<<<dim3(512, 2), 256, 0, stream>>>(Wl3, Wr3, 512, 256, Wt3);

  const int NWG = 391 * 4;  // 1564 (128x128 tiles over [50048 x 512])

  // Layer 1: agg(x fp8) -> Ag; h1 = relu([Ag|Xb]@Wt1 + bl1) -> X1 bf16 + X1f8
  k_aggf128<<<(NN + 1) / 2, 64, 0, stream>>>(Xf8, rowptr, csr_src, csr_w, Ag);
  k_gemm<256, 128, 0, 1><<<NWG, 256, 0, stream>>>(
      Ag, Xb, Wt1, bl1, nullptr, nullptr, nullptr, nullptr, X1, X1f8);

  // Layer 2: agg(h1 fp8) -> Ag; h2 = relu(BN([Ag|h1]@Wt2 + bl2)) -> X2
  k_aggf512<<<NN, 128, 0, stream>>>(X1f8, rowptr, csr_src, csr_w, Ag);
  k_gemm<1024, 512, 1, 0><<<NWG, 256, 0, stream>>>(
      Ag, X1, Wt2, bl2, gamma, beta, mean, var, X2, nullptr);

  // Layer 3: PQ = h2 @ [Wl3|Wr3] -> Ag bf16 + Pf8; h3 = relu(agg(Pf8) + Q + bl3)
  k_gemm<512, 512, 2, 2><<<NWG, 256, 0, stream>>>(
      X2, X2, Wt3, nullptr, nullptr, nullptr, nullptr, nullptr, Ag, Pf8);
  k_aggcomb<<<(NN + 1) / 2, 128, 0, stream>>>(Pf8, Ag, rowptr, csr_src, csr_w, bl3, h3);

  // pool + MLP
  k_zero32<<<(NG * 256 + 255) / 256, 256, 0, stream>>>((u32*)sums, NG * 256);
  k_pool<<<(NN + 127) / 128, 256, 0, stream>>>(h3, batch, sums);
  k_counts<<<1, 64, 0, stream>>>(batch, cnt);
  k_mlp<<<NG, 64, 0, stream>>>(sums, cnt, W4, b4, W5, b5, (float*)d_out);
}

// Round 12
// 429.156 us; speedup vs baseline: 4.5622x; 1.1845x over previous
//
#include <hip/hip_runtime.h>

#define NN 50000
#define NE 800000
#define NG 64
#define BN_EPS 1e-5f

typedef unsigned short u16;
typedef unsigned int u32;
typedef unsigned char u8;
typedef long i64b;
struct alignas(8) us4 { u16 x, y, z, w; };
typedef float f32x4 __attribute__((ext_vector_type(4)));

__device__ inline u16 f2bf_rne(float f) {
  u32 u = __float_as_uint(f);
  return (u16)((u + 0x7fff + ((u >> 16) & 1)) >> 16);
}
__device__ inline int clampi(int v, int lo, int hi) {
  return v < lo ? lo : (v > hi ? hi : v);
}
// async global->LDS DMA, 16B per lane; LDS dest is wave-uniform base
__device__ inline void gload_lds16(const void* g, void* l) {
  __builtin_amdgcn_global_load_lds(
      (const __attribute__((address_space(1))) u32*)g,
      (__attribute__((address_space(3))) u32*)l, 16, 0, 0);
}
// fp8 e4m3 (OCP on gfx950) HW converts
__device__ inline float4 fp8x4f(u32 q) {
  float4 r;
  r.x = __builtin_amdgcn_cvt_f32_fp8(q, 0);
  r.y = __builtin_amdgcn_cvt_f32_fp8(q, 1);
  r.z = __builtin_amdgcn_cvt_f32_fp8(q, 2);
  r.w = __builtin_amdgcn_cvt_f32_fp8(q, 3);
  return r;
}
__device__ inline u32 f4fp8(float a, float b, float c, float d) {
  u32 p = __builtin_amdgcn_cvt_pk_fp8_f32(a, b, 0u, false);
  return __builtin_amdgcn_cvt_pk_fp8_f32(c, d, p, true);
}
__device__ inline u8 f2fp8(float v) {
  return (u8)(__builtin_amdgcn_cvt_pk_fp8_f32(v, 0.f, 0u, false) & 0xffu);
}

// ---------------- utility ----------------
__global__ void k_zero32(u32* __restrict__ p, int n) {
  int i = blockIdx.x * 256 + threadIdx.x;
  if (i < n) p[i] = 0u;
}

// fp32 [N*128] -> fp8 plane
__global__ void k_cvt_x(const float* __restrict__ x, u8* __restrict__ xf8) {
  int i = blockIdx.x * 256 + threadIdx.x;
  if (i >= NN * 128 / 8) return;
  size_t o = (size_t)i * 8;
  float4 a = *(const float4*)(x + o);
  float4 b = *(const float4*)(x + o + 4);
  u32 p0 = f4fp8(a.x, a.y, a.z, a.w);
  u32 p1 = f4fp8(b.x, b.y, b.z, b.w);
  *(uint2*)(xf8 + o) = make_uint2(p0, p1);
}

// ---------------- CSR build (proven) ----------------
__global__ void k_count(const int* __restrict__ dst, int* __restrict__ deg) {
  int e = blockIdx.x * 256 + threadIdx.x;
  if (e < NE) atomicAdd(&deg[clampi(dst[e], 0, NN - 1)], 1);
}

__global__ void k_scan_block(const int* __restrict__ deg, int* __restrict__ excl,
                             int* __restrict__ aux) {
  __shared__ int s[256];
  int t = threadIdx.x;
  int idx = blockIdx.x * 256 + t;
  int v = (idx < NN) ? deg[idx] : 0;
  s[t] = v;
  __syncthreads();
  for (int off = 1; off < 256; off <<= 1) {
    int x = (t >= off) ? s[t - off] : 0;
    __syncthreads();
    s[t] += x;
    __syncthreads();
  }
  if (idx < NN) excl[idx] = s[t] - v;
  if (t == 255) aux[blockIdx.x] = s[255];
}

__global__ void k_scan_aux(int* aux, int nblk) {
  __shared__ int s[256];
  int t = threadIdx.x;
  int v = (t < nblk) ? aux[t] : 0;
  s[t] = v;
  __syncthreads();
  for (int off = 1; off < 256; off <<= 1) {
    int x = (t >= off) ? s[t - off] : 0;
    __syncthreads();
    s[t] += x;
    __syncthreads();
  }
  if (t < nblk) aux[t] = s[t] - v;
}

__global__ void k_fix(int* __restrict__ rowptr, const int* __restrict__ aux,
                      int* __restrict__ cursor) {
  int idx = blockIdx.x * 256 + threadIdx.x;
  if (idx < NN) {
    int v = rowptr[idx] + aux[blockIdx.x];
    rowptr[idx] = v;
    cursor[idx] = v;
  }
  if (idx == 0) rowptr[NN] = NE;
}

__global__ void k_fill(const int* __restrict__ src, const int* __restrict__ dst,
                       const float* __restrict__ ew, int* __restrict__ cursor,
                       int* __restrict__ csr_src, float* __restrict__ csr_w) {
  int e = blockIdx.x * 256 + threadIdx.x;
  if (e < NE) {
    int d = clampi(dst[e], 0, NN - 1);
    int p = atomicAdd(&cursor[d], 1);
    p = clampi(p, 0, NE - 1);
    csr_src[p] = clampi(src[e], 0, NN - 1);
    csr_w[p] = ew[e];
  }
}

// --------- weight prep: Wt[n][k] = [Wl;Wr] concat along k (fp8) ---------
__global__ void k_wt(const float* __restrict__ Wl, const float* __restrict__ Wr,
                     int FIN, int FOUT, u8* __restrict__ t8) {
  int k = blockIdx.y * 256 + threadIdx.x;
  int n = blockIdx.x;
  int K = 2 * FIN;
  if (k >= K) return;
  float v = (k < FIN) ? Wl[(size_t)k * FOUT + n] : Wr[(size_t)(k - FIN) * FOUT + n];
  t8[(size_t)n * K + k] = f2fp8(v);
}

// --------- weight prep: Wt[n][k] = [Wl|Wr] concat along n (fp8) ---------
__global__ void k_wtn(const float* __restrict__ Wl, const float* __restrict__ Wr,
                      int Kdim, int half, u8* __restrict__ t8) {
  int k = blockIdx.y * 256 + threadIdx.x;
  int n = blockIdx.x;
  if (k >= Kdim) return;
  float v = (n < half) ? Wl[(size_t)k * half + n] : Wr[(size_t)k * half + (n - half)];
  t8[(size_t)n * Kdim + k] = f2fp8(v);
}

// ---------------- aggregation (fp8 gather over CSR, fp8 out) ----------------
__global__ void k_aggf512(const u8* __restrict__ xf8, const int* __restrict__ rowptr,
                          const int* __restrict__ csr_src, const float* __restrict__ csr_w,
                          u8* __restrict__ out) {
  int n = blockIdx.x;
  int t = threadIdx.x;  // 0..127
  int beg = rowptr[n], end = rowptr[n + 1];
  float4 acc = {0.f, 0.f, 0.f, 0.f};
  int e = beg;
  for (; e + 2 <= end; e += 2) {
    int s0 = csr_src[e], s1 = csr_src[e + 1];
    float w0 = csr_w[e], w1 = csr_w[e + 1];
    float4 v0 = fp8x4f(*(const u32*)(xf8 + (size_t)s0 * 512 + t * 4));
    float4 v1 = fp8x4f(*(const u32*)(xf8 + (size_t)s1 * 512 + t * 4));
    acc.x += v0.x * w0 + v1.x * w1;
    acc.y += v0.y * w0 + v1.y * w1;
    acc.z += v0.z * w0 + v1.z * w1;
    acc.w += v0.w * w0 + v1.w * w1;
  }
  if (e < end) {
    int s0 = csr_src[e];
    float w0 = csr_w[e];
    float4 v0 = fp8x4f(*(const u32*)(xf8 + (size_t)s0 * 512 + t * 4));
    acc.x += v0.x * w0; acc.y += v0.y * w0;
    acc.z += v0.z * w0; acc.w += v0.w * w0;
  }
  *(u32*)(out + (size_t)n * 512 + t * 4) = f4fp8(acc.x, acc.y, acc.z, acc.w);
}

__global__ void k_aggf128(const u8* __restrict__ xf8, const int* __restrict__ rowptr,
                          const int* __restrict__ csr_src, const float* __restrict__ csr_w,
                          u8* __restrict__ out) {
  int sub = threadIdx.x >> 5;
  int lane = threadIdx.x & 31;
  int n = blockIdx.x * 2 + sub;
  if (n >= NN) return;
  int beg = rowptr[n], end = rowptr[n + 1];
  float4 acc = {0.f, 0.f, 0.f, 0.f};
  int e = beg;
  for (; e + 2 <= end; e += 2) {
    int s0 = csr_src[e], s1 = csr_src[e + 1];
    float w0 = csr_w[e], w1 = csr_w[e + 1];
    float4 v0 = fp8x4f(*(const u32*)(xf8 + (size_t)s0 * 128 + lane * 4));
    float4 v1 = fp8x4f(*(const u32*)(xf8 + (size_t)s1 * 128 + lane * 4));
    acc.x += v0.x * w0 + v1.x * w1;
    acc.y += v0.y * w0 + v1.y * w1;
    acc.z += v0.z * w0 + v1.z * w1;
    acc.w += v0.w * w0 + v1.w * w1;
  }
  if (e < end) {
    int s0 = csr_src[e];
    float w0 = csr_w[e];
    float4 v0 = fp8x4f(*(const u32*)(xf8 + (size_t)s0 * 128 + lane * 4));
    acc.x += v0.x * w0; acc.y += v0.y * w0;
    acc.z += v0.z * w0; acc.w += v0.w * w0;
  }
  *(u32*)(out + (size_t)n * 128 + lane * 4) = f4fp8(acc.x, acc.y, acc.z, acc.w);
}

// ------- fp8 MFMA GEMM: O8[128x128 tiles] over A=[A0|A1], Wt[n][k] fp8 -------
// FOUT fixed 512. EPI: 0 = relu(v+bias); 1 = relu(BN(v+bias)); 2 = raw v.
// BK=128 fp8 (128B/row). global_load_lds w16, pre-swizzled src (16B-chunk XOR),
// XOR-swizzled ds_read_b64 frags, LDS-restaged coalesced fp8 output.
template <int K, int W0, int EPI>
__global__ __launch_bounds__(256) void k_gemm(
    const u8* __restrict__ A0, const u8* __restrict__ A1,
    const u8* __restrict__ Wt, const float* __restrict__ bias,
    const float* __restrict__ gamma, const float* __restrict__ beta,
    const float* __restrict__ mean, const float* __restrict__ var,
    u8* __restrict__ O8g) {
  constexpr int FOUT = 512;
  __shared__ char LDSC[32768];
  u8* AS = (u8*)LDSC;            // 16 KB A tile [128 rows][128 k fp8]
  u8* BS = (u8*)(LDSC + 16384);  // 16 KB B tile [128 cols][128 k fp8]
  int tid = threadIdx.x;
  int wid = tid >> 6, l = tid & 63;
  int wr = wid >> 1, wc = wid & 1;

  // bijective XCD swizzle + quad mapping
  int nwg = gridDim.x;  // 1564
  int q8 = nwg >> 3, r8 = nwg & 7;
  int xcd = blockIdx.x & 7, idx = blockIdx.x >> 3;
  int L = (xcd < r8 ? xcd * (q8 + 1) : r8 * (q8 + 1) + (xcd - r8) * q8) + idx;
  int n0 = (L >> 2) * 128, c0 = (L & 3) * 128;

  f32x4 acc[4][4] = {};

  int srw = 32 * wid + (l >> 3);  // staged row (+8j), 8 rows per instr
  int sch = l & 7;                // 16B chunk within 128B row

  for (int k0 = 0; k0 < K; k0 += 128) {
    __syncthreads();
    {
      const u8* s; int rs; int seg;
      if (k0 < W0) { s = A0; rs = W0; seg = k0; }
      else         { s = A1; rs = K - W0; seg = k0 - W0; }
#pragma unroll
      for (int j = 0; j < 4; ++j) {
        int r = srw + 8 * j;
        int gr = n0 + r;
        if (gr >= NN) gr = NN - 1;
        int cc = sch ^ (r & 7);
        gload_lds16(s + (size_t)gr * rs + seg + cc * 16, AS + (32 * wid + 8 * j) * 128);
      }
#pragma unroll
      for (int j = 0; j < 4; ++j) {
        int r = srw + 8 * j;
        int cc = sch ^ (r & 7);
        gload_lds16(Wt + (size_t)(c0 + r) * K + k0 + cc * 16, BS + (32 * wid + 8 * j) * 128);
      }
    }
    __syncthreads();

#pragma unroll
    for (int ks = 0; ks < 4; ++ks) {
      i64b b[4];
#pragma unroll
      for (int n = 0; n < 4; ++n) {
        int col = wc * 64 + n * 16 + (l & 15);
        int byte = (col * 128 + ks * 32 + ((l >> 4) << 3)) ^ ((col & 7) << 4);
        b[n] = *(const i64b*)((const char*)BS + byte);
      }
#pragma unroll
      for (int m = 0; m < 4; ++m) {
        int row = wr * 64 + m * 16 + (l & 15);
        int byte = (row * 128 + ks * 32 + ((l >> 4) << 3)) ^ ((row & 7) << 4);
        i64b a = *(const i64b*)((const char*)AS + byte);
#pragma unroll
        for (int n = 0; n < 4; ++n)
          acc[m][n] = __builtin_amdgcn_mfma_f32_16x16x32_fp8_fp8(a, b[n], acc[m][n], 0, 0, 0);
      }
    }
  }

  // ---- epilogue: EPI -> LDS restage (swizzled u8) -> coalesced 16B stores ----
  __syncthreads();
  u8* O8 = (u8*)LDSC;  // [128][128] u8 = 16 KB
#pragma unroll
  for (int n = 0; n < 4; ++n) {
    int colL = wc * 64 + n * 16 + (l & 15);
    int col = c0 + colL;
    float bs = (EPI == 2) ? 0.f : bias[col];
    float sc = 1.f, sf = 0.f;
    if (EPI == 1) {
      sc = rsqrtf(var[col] + BN_EPS) * gamma[col];
      sf = beta[col] - mean[col] * sc;
    }
#pragma unroll
    for (int m = 0; m < 4; ++m) {
      int rowL0 = wr * 64 + m * 16 + ((l >> 4) << 2);
#pragma unroll
      for (int r = 0; r < 4; ++r) {
        float v = acc[m][n][r];
        if (EPI != 2) {
          v += bs;
          if (EPI == 1) v = v * sc + sf;
          v = fmaxf(v, 0.f);
        }
        int rowL = rowL0 + r;
        int byte = (rowL * 128 + colL) ^ ((rowL & 7) << 4);
        O8[byte] = f2fp8(v);
      }
    }
  }
  __syncthreads();
#pragma unroll
  for (int i = 0; i < 4; ++i) {
    int chunk = i * 256 + tid;   // 0..1023 chunks of 16B
    int rowL = chunk >> 3;
    int cs = (chunk & 7) * 16;
    int rr = n0 + rowL;
    if (rr < NN) {
      int byte = (rowL * 128 + cs) ^ ((rowL & 7) << 4);
      *(uint4*)(O8g + (size_t)rr * FOUT + c0 + cs) = *(const uint4*)((const char*)O8 + byte);
    }
  }
}

// ------- L3 combine: h3 = relu(agg256(P) + Q + bl3); PQ fp8 [N,512] -------
__global__ void k_aggcomb(const u8* __restrict__ PQ, const int* __restrict__ rowptr,
                          const int* __restrict__ csr_src, const float* __restrict__ csr_w,
                          const float* __restrict__ bl3, float* __restrict__ h3) {
  int sub = threadIdx.x >> 6;
  int lane = threadIdx.x & 63;
  int n = blockIdx.x * 2 + sub;
  if (n >= NN) return;
  int beg = rowptr[n], end = rowptr[n + 1];
  float4 acc = {0.f, 0.f, 0.f, 0.f};
  int e = beg;
  for (; e + 2 <= end; e += 2) {
    int s0 = csr_src[e], s1 = csr_src[e + 1];
    float w0 = csr_w[e], w1 = csr_w[e + 1];
    float4 v0 = fp8x4f(*(const u32*)(PQ + (size_t)s0 * 512 + lane * 4));
    float4 v1 = fp8x4f(*(const u32*)(PQ + (size_t)s1 * 512 + lane * 4));
    acc.x += v0.x * w0 + v1.x * w1;
    acc.y += v0.y * w0 + v1.y * w1;
    acc.z += v0.z * w0 + v1.z * w1;
    acc.w += v0.w * w0 + v1.w * w1;
  }
  if (e < end) {
    int s0 = csr_src[e];
    float w0 = csr_w[e];
    float4 v0 = fp8x4f(*(const u32*)(PQ + (size_t)s0 * 512 + lane * 4));
    acc.x += v0.x * w0; acc.y += v0.y * w0;
    acc.z += v0.z * w0; acc.w += v0.w * w0;
  }
  float4 qv = fp8x4f(*(const u32*)(PQ + (size_t)n * 512 + 256 + lane * 4));
  float4 bb = *(const float4*)(bl3 + lane * 4);
  float4 o;
  o.x = fmaxf(acc.x + qv.x + bb.x, 0.f);
  o.y = fmaxf(acc.y + qv.y + bb.y, 0.f);
  o.z = fmaxf(acc.z + qv.z + bb.z, 0.f);
  o.w = fmaxf(acc.w + qv.w + bb.w, 0.f);
  *(float4*)(h3 + (size_t)n * 256 + lane * 4) = o;
}

// ---------------- pooling + MLP ----------------
__global__ void k_counts(const int* __restrict__ batch, float* __restrict__ cnt) {
  int g = threadIdx.x;  // 64 threads
  int lo = 0, hi = NN;
  while (lo < hi) { int m = (lo + hi) >> 1; if (batch[m] < g) lo = m + 1; else hi = m; }
  int a = lo;
  lo = 0; hi = NN;
  int g1 = g + 1;
  while (lo < hi) { int m = (lo + hi) >> 1; if (batch[m] < g1) lo = m + 1; else hi = m; }
  cnt[g] = (float)(lo - a);
}

__global__ void k_pool(const float* __restrict__ h, const int* __restrict__ batch,
                       float* __restrict__ sums) {
  int f = threadIdx.x;  // 256 features
  int n0 = blockIdx.x * 128;
  int n1 = n0 + 128; if (n1 > NN) n1 = NN;
  float acc = 0.f;
  int cur = clampi(batch[n0], 0, NG - 1);
  for (int n = n0; n < n1; ++n) {
    int g = clampi(batch[n], 0, NG - 1);
    if (g != cur) {
      atomicAdd(&sums[(size_t)cur * 256 + f], acc);
      acc = 0.f;
      cur = g;
    }
    acc += h[(size_t)n * 256 + f];
  }
  atomicAdd(&sums[(size_t)cur * 256 + f], acc);
}

__global__ void k_mlp(const float* __restrict__ sums, const float* __restrict__ cnt,
                      const float* __restrict__ W4, const float* __restrict__ b4,
                      const float* __restrict__ W5, const float* __restrict__ b5,
                      float* __restrict__ out) {
  __shared__ float g[256];
  int b = blockIdx.x, t = threadIdx.x;  // 64 threads
  float inv = 1.f / fmaxf(cnt[b], 1.f);
#pragma unroll
  for (int q = 0; q < 4; ++q) g[q * 64 + t] = sums[(size_t)b * 256 + q * 64 + t] * inv;
  __syncthreads();
  float acc = 0.f;
#pragma unroll 8
  for (int k = 0; k < 256; ++k) acc += g[k] * W4[k * 64 + t];
  float a = fmaxf(acc + b4[t], 0.f) * W5[t];
  for (int off = 32; off; off >>= 1) a += __shfl_down(a, off, 64);
  if (t == 0) out[b] = fmaxf(a + b5[0], 0.f);
}

// ---------------- launcher ----------------
extern "C" void kernel_launch(void* const* d_in, const int* in_sizes, int n_in,
                              void* d_out, int out_size, void* d_ws, size_t ws_size,
                              hipStream_t stream) {
  const float* x     = (const float*)d_in[0];
  const int*   eidx  = (const int*)d_in[1];
  const float* ew    = (const float*)d_in[2];
  const int*   batch = (const int*)d_in[3];
  const float* Wl1 = (const float*)d_in[4];
  const float* bl1 = (const float*)d_in[5];
  const float* Wr1 = (const float*)d_in[6];
  const float* Wl2 = (const float*)d_in[7];
  const float* bl2 = (const float*)d_in[8];
  const float* Wr2 = (const float*)d_in[9];
  const float* Wl3 = (const float*)d_in[10];
  const float* bl3 = (const float*)d_in[11];
  const float* Wr3 = (const float*)d_in[12];
  const float* gamma = (const float*)d_in[13];
  const float* beta  = (const float*)d_in[14];
  const float* mean  = (const float*)d_in[15];
  const float* var   = (const float*)d_in[16];
  const float* W4 = (const float*)d_in[17];
  const float* b4 = (const float*)d_in[18];
  const float* W5 = (const float*)d_in[19];
  const float* b5 = (const float*)d_in[20];

  const int* src = eidx;
  const int* dst = eidx + NE;

  // ---- workspace layout (~145 MB; ws_size known >= 313 MB) ----
  const size_t P8 = (size_t)NN * 512;      // 25.6 MB fp8 plane
  char* w = (char*)d_ws;
  u8*  X1f8 = (u8*)w; w += P8;             // h1 fp8
  u8*  X2f8 = (u8*)w; w += P8;             // h2 fp8
  u8*  Agf8 = (u8*)w; w += P8;             // agg stream; later PQ plane
  u8*  Xf8  = (u8*)w; w += (size_t)NN * 128;
  float* h3 = (float*)w; w += (size_t)NN * 256 * 4;  // 51.2 MB fp32
  u8* Wt1 = (u8*)w; w += (size_t)512 * 256;
  u8* Wt2 = (u8*)w; w += (size_t)512 * 1024;
  u8* Wt3 = (u8*)w; w += (size_t)512 * 512;
  int*   csr_src = (int*)w;   w += (size_t)NE * 4;
  float* csr_w   = (float*)w; w += (size_t)NE * 4;
  int*   rowptr  = (int*)w;   w += ((size_t)NN + 4) * 4;
  int*   cursor  = (int*)w;   w += (size_t)NN * 4;
  int*   aux     = (int*)w;   w += 1024;
  float* sums    = (float*)w; w += (size_t)NG * 256 * 4;
  float* cnt     = (float*)w; w += 1024;

  int nblk = (NN + 255) / 256;  // 196

  // CSR build + input conversion + weight prep
  k_zero32<<<nblk, 256, 0, stream>>>((u32*)cursor, NN);
  k_count<<<(NE + 255) / 256, 256, 0, stream>>>(dst, cursor);
  k_scan_block<<<nblk, 256, 0, stream>>>(cursor, rowptr, aux);
  k_scan_aux<<<1, 256, 0, stream>>>(aux, nblk);
  k_fix<<<nblk, 256, 0, stream>>>(rowptr, aux, cursor);
  k_fill<<<(NE + 255) / 256, 256, 0, stream>>>(src, dst, ew, cursor, csr_src, csr_w);
  k_cvt_x<<<(NN * 128 / 8 + 255) / 256, 256, 0, stream>>>(x, Xf8);
  k_wt<<<dim3(512, 1), 256, 0, stream>>>(Wl1, Wr1, 128, 512, Wt1);
  k_wt<<<dim3(512, 4), 256, 0, stream>>>(Wl2, Wr2, 512, 512, Wt2);
  k_wtn<<<dim3(512, 2), 256, 0, stream>>>(Wl3, Wr3, 512, 256, Wt3);

  const int NWG = 391 * 4;  // 1564 (128x128 tiles over [50048 x 512])

  // Layer 1: agg(x fp8) -> Ag; h1 = relu([Ag|Xf8]@Wt1 + bl1) -> X1f8
  k_aggf128<<<(NN + 1) / 2, 64, 0, stream>>>(Xf8, rowptr, csr_src, csr_w, Agf8);
  k_gemm<256, 128, 0><<<NWG, 256, 0, stream>>>(
      Agf8, Xf8, Wt1, bl1, nullptr, nullptr, nullptr, nullptr, X1f8);

  // Layer 2: agg(h1 fp8) -> Ag; h2 = relu(BN([Ag|h1]@Wt2 + bl2)) -> X2f8
  k_aggf512<<<NN, 128, 0, stream>>>(X1f8, rowptr, csr_src, csr_w, Agf8);
  k_gemm<1024, 512, 1><<<NWG, 256, 0, stream>>>(
      Agf8, X1f8, Wt2, bl2, gamma, beta, mean, var, X2f8);

  // Layer 3: PQ = h2 @ [Wl3|Wr3] -> Agf8 (raw); h3 = relu(agg(P) + Q + bl3)
  k_gemm<512, 512, 2><<<NWG, 256, 0, stream>>>(
      X2f8, X2f8, Wt3, nullptr, nullptr, nullptr, nullptr, nullptr, Agf8);
  k_aggcomb<<<(NN + 1) / 2, 128, 0, stream>>>(Agf8, rowptr, csr_src, csr_w, bl3, h3);

  // pool + MLP
  k_zero32<<<(NG * 256 + 255) / 256, 256, 0, stream>>>((u32*)sums, NG * 256);
  k_pool<<<(NN + 127) / 128, 256, 0, stream>>>(h3, batch, sums);
  k_counts<<<1, 64, 0, stream>>>(batch, cnt);
  k_mlp<<<NG, 64, 0, stream>>>(sums, cnt, W4, b4, W5, b5, (float*)d_out);
}